// Round 6
// baseline (2992.317 us; speedup 1.0000x reference)
//
#include <hip/hip_runtime.h>

#define NN   10240
#define EE   320000
#define BGR  64
#define NPG  160
#define KK   16
#define DINF 25
#define DD   256
#define LL   4
#define LNEPS 1e-5f

#define GRID_BLKS 768   // capacity is 1024 (4/CU by 37888B LDS); 768 leaves 1.33x margin

typedef unsigned short ushort_t;
typedef __attribute__((ext_vector_type(8))) short s8v;
typedef __attribute__((ext_vector_type(4))) float f4v;

__device__ __forceinline__ float bf2f(ushort_t u) {
  union { unsigned u; float f; } a; a.u = ((unsigned)u) << 16; return a.f;
}
__device__ __forceinline__ ushort_t f2bf(float f) {
  union { float f; unsigned u; } a; a.f = f;
  unsigned r = (a.u + 0x7fffu + ((a.u >> 16) & 1u)) >> 16;   // RNE
  return (ushort_t)r;
}

// async global->LDS DMA, 16B per lane, dest = wave-uniform base + lane*16
__device__ __forceinline__ void gld16(const void* g, void* l) {
  __builtin_amdgcn_global_load_lds(
      (const __attribute__((address_space(1))) unsigned int*)g,
      (__attribute__((address_space(3))) unsigned int*)l, 16, 0, 0);
}

// ---------------- grid barrier: epoch + arrival counter, agent scope ----------------
// cnt/epoch zeroed by host memset before launch. Every block calls with the same
// monotonically increasing et. HANG-PROOF: spinners escape after ~0.3s (degrades to
// wrong answer, never a watchdog kill). Threshold is ~1000x the worst phase skew.
__device__ __forceinline__ void gridbar(int* cnt, int* epoch, int nb, int et) {
  __threadfence();
  __syncthreads();
  if (threadIdx.x == 0) {
    int t = __hip_atomic_fetch_add(cnt, 1, __ATOMIC_ACQ_REL, __HIP_MEMORY_SCOPE_AGENT);
    if (t == nb - 1) {
      __hip_atomic_store(cnt, 0, __ATOMIC_RELAXED, __HIP_MEMORY_SCOPE_AGENT);
      __hip_atomic_fetch_add(epoch, 1, __ATOMIC_RELEASE, __HIP_MEMORY_SCOPE_AGENT);
    } else {
      int spins = 0;
      while (__hip_atomic_load(epoch, __ATOMIC_ACQUIRE, __HIP_MEMORY_SCOPE_AGENT) < et) {
        __builtin_amdgcn_s_sleep(8);
        if (++spins > (1 << 20)) break;    // ~0.3s escape hatch
      }
    }
  }
  __syncthreads();
  __threadfence();
}

// ---------------- block reduce (256 threads = 4 waves) ----------------
__device__ __forceinline__ float2 block_reduce2(float a, float b, float* red) {
  __syncthreads();
  #pragma unroll
  for (int off = 32; off > 0; off >>= 1) {
    a += __shfl_down(a, off);
    b += __shfl_down(b, off);
  }
  int lane = threadIdx.x & 63;
  int wid  = threadIdx.x >> 6;
  if (lane == 0) { red[wid * 2] = a; red[wid * 2 + 1] = b; }
  __syncthreads();
  float sa = red[0] + red[2] + red[4] + red[6];
  float sb = red[1] + red[3] + red[5] + red[7];
  return make_float2(sa, sb);
}

// ================= phase bodies (identical math to the verified 275us build) ==========

// weight transpose + hi/lo split for layers 1-3; wp in [0,96)
__device__ __forceinline__ void wprep_body(int wp, const float* __restrict__ Wi,
                                           const float* __restrict__ Wo,
                                           ushort_t* __restrict__ BT, char* smem) {
  int t = threadIdx.x;
  float (*tile)[65] = (float (*)[65])smem;     // 64x65 floats = 16640 B
  int l = wp >> 5, rem = wp & 31;
  int kb = rem >> 2, nb = rem & 3;
  int k0 = kb * 64, n0 = nb * 64;
  const float* Wl = (k0 < 256) ? (Wi + (size_t)l * 65536 + (size_t)k0 * 256)
                               : (Wo + (size_t)l * 65536 + (size_t)(k0 - 256) * 256);
  #pragma unroll
  for (int p = 0; p < 4; p++) {
    int ks = p * 16 + (t >> 4);
    int n  = (t & 15) * 4;
    float4 v = *(const float4*)&Wl[(size_t)ks * 256 + n0 + n];
    tile[ks][n] = v.x; tile[ks][n + 1] = v.y; tile[ks][n + 2] = v.z; tile[ks][n + 3] = v.w;
  }
  __syncthreads();
  ushort_t* BTl = BT + (size_t)l * 262144;
  #pragma unroll
  for (int p = 0; p < 2; p++) {
    int n  = p * 32 + (t >> 3);
    int kk = (t & 7) * 8;
    ushort_t hi[8], lo[8];
    #pragma unroll
    for (int j = 0; j < 8; j++) {
      float v = tile[kk + j][n];
      hi[j] = f2bf(v);
      lo[j] = f2bf(v - bf2f(hi[j]));
    }
    *(s8v*)&BTl[(size_t)(n0 + n) * 1024 + k0 + kk]       = *(const s8v*)hi;
    *(s8v*)&BTl[(size_t)(n0 + n) * 1024 + 512 + k0 + kk] = *(const s8v*)lo;
  }
  __syncthreads();
}

// layer-0 weight prep; wp in [96,224)
__device__ __forceinline__ void bt0_body(int wp, const float* __restrict__ Wi0,
                                         const float* __restrict__ Wo0,
                                         ushort_t* __restrict__ BT0) {
  int idx = (wp - 96) * 256 + threadIdx.x;   // n*128 + k
  int n = idx >> 7, k = idx & 127;
  int ks = k & 63;
  float v = 0.f;
  if (ks < DINF) v = Wi0[ks * 256 + n];
  else if (ks < 2 * DINF) v = Wo0[(ks - DINF) * 256 + n];
  ushort_t hi = f2bf(v);
  BT0[idx] = (k < 64) ? hi : f2bf(v - bf2f(hi));
}

// regloss partials; rb in [0,64)
__device__ __forceinline__ void regloss_body(int rb, const float* __restrict__ Wo0,
                                             const float* __restrict__ b_out0,
                                             const float* __restrict__ Wo,
                                             const float* __restrict__ b_out,
                                             float* __restrict__ partials, char* smem) {
  int t = threadIdx.x;
  int tid = rb * 256 + t;
  int stride = 64 * 256;
  float sum = 0.f;
  for (int i = tid; i < DINF * DD; i += stride)          sum += fabsf(Wo0[i]);
  for (int i = tid; i < DD; i += stride)                 sum += fabsf(b_out0[i]);
  for (int i = tid; i < (LL - 1) * DD * DD; i += stride) sum += fabsf(Wo[i]);
  for (int i = tid; i < (LL - 1) * DD; i += stride)      sum += fabsf(b_out[i]);
  float* red = (float*)smem;
  float2 ss = block_reduce2(sum, 0.f, red);
  if (t == 0) partials[rb] = ss.x;
}

// single-block full scan: deg -> dinv + row_ptr + cursor (256 thr x 40 nodes)
__device__ __forceinline__ void scan_body(const int* __restrict__ deg,
                                          float* __restrict__ dinv,
                                          int* __restrict__ row_ptr,
                                          int* __restrict__ cursor, char* smem) {
  int t = threadIdx.x;
  int base = t * 40;
  int dd[40];
  int sum = 0;
  #pragma unroll
  for (int i = 0; i < 10; i++) {
    int4 d4 = *(const int4*)&deg[base + i * 4];
    dd[i * 4] = d4.x; dd[i * 4 + 1] = d4.y; dd[i * 4 + 2] = d4.z; dd[i * 4 + 3] = d4.w;
    sum += d4.x + d4.y + d4.z + d4.w;
  }
  int lane = t & 63, wid = t >> 6;
  int v = sum;
  #pragma unroll
  for (int off = 1; off < 64; off <<= 1) {
    int u = __shfl_up(v, off);
    if (lane >= off) v += u;
  }
  int* ws = (int*)smem;
  if (lane == 63) ws[wid] = v;
  __syncthreads();
  int woff = 0;
  #pragma unroll
  for (int p = 0; p < 4; p++) woff += (p < wid) ? ws[p] : 0;
  int rp = woff + v - sum;
  #pragma unroll
  for (int i = 0; i < 10; i++) {
    int4 rr; float4 dv;
    rr.x = rp; dv.x = rsqrtf((float)max(dd[i * 4], 1));     rp += dd[i * 4];
    rr.y = rp; dv.y = rsqrtf((float)max(dd[i * 4 + 1], 1)); rp += dd[i * 4 + 1];
    rr.z = rp; dv.z = rsqrtf((float)max(dd[i * 4 + 2], 1)); rp += dd[i * 4 + 2];
    rr.w = rp; dv.w = rsqrtf((float)max(dd[i * 4 + 3], 1)); rp += dd[i * 4 + 3];
    *(int4*)&row_ptr[base + i * 4] = rr;
    *(int4*)&cursor[base + i * 4]  = rr;
    *(float4*)&dinv[base + i * 4]  = dv;
  }
  if (t == 0) row_ptr[NN] = EE;
}

// layer-0 per-node aggregation (whole wave on one node)
__device__ __forceinline__ void agg0_node(const float* __restrict__ x,
                                          const int2* __restrict__ epk,
                                          int e0, int e1, int lane,
                                          ushort_t* __restrict__ out) {
  int half = lane >> 5;
  int ch = lane & 31;
  int chc = (ch < DINF) ? ch : 0;
  float accI = 0.f, accO = 0.f;
  for (int c0 = e0; c0 < e1; c0 += 64) {
    int cnt = min(64, e1 - c0);
    int2 my = (lane < cnt) ? epk[c0 + lane] : make_int2(0, 0);
    int i = half;
    for (; i + 6 < cnt; i += 8) {
      unsigned u[4]; float wt[4], vv[4];
      #pragma unroll
      for (int j = 0; j < 4; j++) {
        u[j]  = (unsigned)__shfl(my.x, i + 2 * j);
        wt[j] = __int_as_float(__shfl(my.y, i + 2 * j));
      }
      #pragma unroll
      for (int j = 0; j < 4; j++)
        vv[j] = x[(size_t)(u[j] & 0x7fffffffu) * DINF + chc];
      #pragma unroll
      for (int j = 0; j < 4; j++) {
        float wI = (u[j] >> 31) ? wt[j] : 0.f;  float wO = wt[j] - wI;
        accI = fmaf(vv[j], wI, accI); accO = fmaf(vv[j], wO, accO);
      }
    }
    for (; i < cnt; i += 2) {
      unsigned u = (unsigned)__shfl(my.x, i);
      float wt = __int_as_float(__shfl(my.y, i));
      float vv = x[(size_t)(u & 0x7fffffffu) * DINF + chc];
      float wI = (u >> 31) ? wt : 0.f;  float wO = wt - wI;
      accI = fmaf(vv, wI, accI); accO = fmaf(vv, wO, accO);
    }
  }
  accI += __shfl_xor(accI, 32);
  accO += __shfl_xor(accO, 32);
  if (half == 0) {
    if (ch < DINF) {
      out[ch]        = f2bf(accI);
      out[DINF + ch] = f2bf(accO);
    } else {
      int k = 2 * DINF + (ch - DINF) * 2;
      out[k] = 0;
      out[k + 1] = 0;
    }
  }
}

// layers 1-3 per-node aggregation (whole wave on one node, scalar metadata)
__device__ __forceinline__ void agg_node(const ushort_t* __restrict__ h,
                                         const int2* __restrict__ epk,
                                         const int* __restrict__ row_ptr,
                                         int n, int lane,
                                         ushort_t* __restrict__ out) {
  int coff = lane * 4;
  int e0 = __builtin_amdgcn_readfirstlane(row_ptr[n]);
  int e1 = __builtin_amdgcn_readfirstlane(row_ptr[n + 1]);
  float aI0 = 0.f, aI1 = 0.f, aI2 = 0.f, aI3 = 0.f;
  float aO0 = 0.f, aO1 = 0.f, aO2 = 0.f, aO3 = 0.f;
  int i = e0;
  for (; i + 8 <= e1; i += 8) {
    int2 e[8];
    #pragma unroll
    for (int j = 0; j < 8; j++) e[j] = epk[i + j];
    ushort4 v[8];
    #pragma unroll
    for (int j = 0; j < 8; j++)
      v[j] = *(const ushort4*)&h[(size_t)(unsigned)(e[j].x & 0x7fffffff) * 256u + coff];
    #pragma unroll
    for (int j = 0; j < 8; j++) {
      float wt = __int_as_float(e[j].y);
      float wI = (e[j].x < 0) ? wt : 0.f;  float wO = wt - wI;
      float f;
      f = bf2f(v[j].x); aI0 = fmaf(f, wI, aI0); aO0 = fmaf(f, wO, aO0);
      f = bf2f(v[j].y); aI1 = fmaf(f, wI, aI1); aO1 = fmaf(f, wO, aO1);
      f = bf2f(v[j].z); aI2 = fmaf(f, wI, aI2); aO2 = fmaf(f, wO, aO2);
      f = bf2f(v[j].w); aI3 = fmaf(f, wI, aI3); aO3 = fmaf(f, wO, aO3);
    }
  }
  for (; i < e1; i++) {
    int2 e = epk[i];
    ushort4 v = *(const ushort4*)&h[(size_t)(unsigned)(e.x & 0x7fffffff) * 256u + coff];
    float wt = __int_as_float(e.y);
    float wI = (e.x < 0) ? wt : 0.f;  float wO = wt - wI;
    float f;
    f = bf2f(v.x); aI0 = fmaf(f, wI, aI0); aO0 = fmaf(f, wO, aO0);
    f = bf2f(v.y); aI1 = fmaf(f, wI, aI1); aO1 = fmaf(f, wO, aO1);
    f = bf2f(v.z); aI2 = fmaf(f, wI, aI2); aO2 = fmaf(f, wO, aO2);
    f = bf2f(v.w); aI3 = fmaf(f, wI, aI3); aO3 = fmaf(f, wO, aO3);
  }
  ushort4 pI, pO;
  pI.x = f2bf(aI0); pI.y = f2bf(aI1); pI.z = f2bf(aI2); pI.w = f2bf(aI3);
  pO.x = f2bf(aO0); pO.y = f2bf(aO1); pO.z = f2bf(aO2); pO.w = f2bf(aO3);
  *(ushort4*)&out[coff]       = pI;
  *(ushort4*)&out[256 + coff] = pO;
}

// MFMA GEMM + bias + LayerNorm + ReLU for one 32-row tile.
// smem layout: As @0 (4096B), Bs @4096 (32768B), redS @36864, redQ @37376. total 37888.
#define GEMM_SMEM 37888
template <int KB>
__device__ __forceinline__ void gemm_block(const ushort_t* __restrict__ A,
                                           const ushort_t* __restrict__ BT,
                                           const float* __restrict__ bi,
                                           const float* __restrict__ bo,
                                           const float* __restrict__ g,
                                           const float* __restrict__ bb,
                                           ushort_t* __restrict__ hout,
                                           int m0, char* smem) {
  constexpr int AK = KB / 2;               // A row length (shorts)
  constexpr int ABR = AK * 2;              // A row bytes
  constexpr int BBR = KB * 2;              // BT row bytes
  ushort_t* As = (ushort_t*)smem;
  ushort_t* Bs = (ushort_t*)(smem + 4096);
  float (*redS)[4] = (float (*)[4])(smem + 36864);
  float (*redQ)[4] = (float (*)[4])(smem + 37376);
  int t = threadIdx.x;
  int w = t >> 6;
  int lane = t & 63;
  int q = lane >> 4, n16 = lane & 15;
  int sx = (n16 & 7) << 3;                 // read-side swizzle (short units)
  f4v acc[2][4];
  #pragma unroll
  for (int rt = 0; rt < 2; rt++)
    #pragma unroll
    for (int ct = 0; ct < 4; ct++) acc[rt][ct] = (f4v){0.f, 0.f, 0.f, 0.f};

  int srow   = lane >> 3;
  int sobyte = (lane & 7) * 16;
  int arow   = w * 8 + srow;
  size_t a_base = (size_t)(m0 + arow) * ABR
                + (size_t)((unsigned)sobyte ^ ((unsigned)(arow & 7) << 4));
  char* as_dst = (char*)As + w * 1024;
  char* bs_dst = (char*)Bs + w * 8192;

  for (int k0 = 0; k0 < KB; k0 += 64) {
    __syncthreads();                       // previous tile fully consumed
    gld16((const char*)A + a_base + (size_t)((k0 & (AK - 1)) * 2), as_dst);
    #pragma unroll
    for (int j = 0; j < 8; j++) {
      int brow = w * 64 + j * 8 + srow;
      gld16((const char*)BT + (size_t)brow * BBR + (size_t)(k0 * 2)
                + (size_t)((unsigned)sobyte ^ ((unsigned)(brow & 7) << 4)),
            bs_dst + j * 1024);
    }
    asm volatile("s_waitcnt vmcnt(0)" ::: "memory");
    __syncthreads();                       // tile ready
    #pragma unroll
    for (int kk = 0; kk < 2; kk++) {
      int ko = (kk * 32 + q * 8) ^ sx;
      s8v af0 = *(const s8v*)&As[n16 * 64 + ko];
      s8v af1 = *(const s8v*)&As[(16 + n16) * 64 + ko];
      #pragma unroll
      for (int ct = 0; ct < 4; ct++) {
        s8v bf = *(const s8v*)&Bs[(w * 64 + ct * 16 + n16) * 64 + ko];
        acc[0][ct] = __builtin_amdgcn_mfma_f32_16x16x32_bf16(af0, bf, acc[0][ct], 0, 0, 0);
        acc[1][ct] = __builtin_amdgcn_mfma_f32_16x16x32_bf16(af1, bf, acc[1][ct], 0, 0, 0);
      }
    }
  }

  float biv[4], gv[4], bbv[4];
  #pragma unroll
  for (int ct = 0; ct < 4; ct++) {
    int c = w * 64 + ct * 16 + n16;
    biv[ct] = bi[c] + bo[c];
    gv[ct]  = g[c];
    bbv[ct] = bb[c];
  }
  #pragma unroll
  for (int rt = 0; rt < 2; rt++)
    #pragma unroll
    for (int rg = 0; rg < 4; rg++) {
      float s = 0.f, ss = 0.f;
      #pragma unroll
      for (int ct = 0; ct < 4; ct++) {
        float v = acc[rt][ct][rg] + biv[ct];
        s += v; ss += v * v;
      }
      #pragma unroll
      for (int off = 1; off < 16; off <<= 1) {
        s  += __shfl_xor(s, off);
        ss += __shfl_xor(ss, off);
      }
      if (n16 == 0) {
        int row = rt * 16 + q * 4 + rg;
        redS[row][w] = s;
        redQ[row][w] = ss;
      }
    }
  __syncthreads();
  #pragma unroll
  for (int rt = 0; rt < 2; rt++)
    #pragma unroll
    for (int rg = 0; rg < 4; rg++) {
      int row = rt * 16 + q * 4 + rg;
      float mean = (redS[row][0] + redS[row][1] + redS[row][2] + redS[row][3]) * (1.f / 256.f);
      float var  = (redQ[row][0] + redQ[row][1] + redQ[row][2] + redQ[row][3]) * (1.f / 256.f)
                   - mean * mean;
      float rs = rsqrtf(fmaxf(var, 0.f) + LNEPS);
      #pragma unroll
      for (int ct = 0; ct < 4; ct++) {
        float v = acc[rt][ct][rg] + biv[ct];
        float o = fmaxf((v - mean) * rs * gv[ct] + bbv[ct], 0.f);
        hout[(size_t)(m0 + row) * 256 + w * 64 + ct * 16 + n16] = f2bf(o);
      }
    }
}

// fragment pooling + LN + mask for one (b,k).  smem: list @0 (640B), cnt @640, red @656.
__device__ __forceinline__ void frag_block(const ushort_t* __restrict__ h,
                                           const int* __restrict__ fid,
                                           const float* __restrict__ g,
                                           const float* __restrict__ bb,
                                           float* __restrict__ out_emb,
                                           float* __restrict__ out_mask,
                                           int b, int k, char* smem) {
  int d = threadIdx.x;
  int* list = (int*)smem;
  int* cntp = (int*)(smem + 640);
  float* red = (float*)(smem + 656);
  if (d == 0) *cntp = 0;
  __syncthreads();
  int base = b * NPG;
  if (d < NPG) {
    if (fid[base + d] == k) { int p = atomicAdd(cntp, 1); list[p] = d; }
  }
  __syncthreads();
  int c = *cntp;
  float acc = 0.f;
  int i = 0;
  for (; i + 4 <= c; i += 4) {
    int l0 = list[i], l1 = list[i + 1], l2 = list[i + 2], l3 = list[i + 3];
    float a0 = bf2f(h[(size_t)(base + l0) * 256 + d]);
    float a1 = bf2f(h[(size_t)(base + l1) * 256 + d]);
    float a2 = bf2f(h[(size_t)(base + l2) * 256 + d]);
    float a3 = bf2f(h[(size_t)(base + l3) * 256 + d]);
    acc += (a0 + a1) + (a2 + a3);
  }
  for (; i < c; i++) {
    acc += bf2f(h[(size_t)(base + list[i]) * 256 + d]);
  }
  float2 ss = block_reduce2(acc, acc * acc, red);
  float mean = ss.x * (1.f / 256.f);
  float var  = ss.y * (1.f / 256.f) - mean * mean;
  float o = (acc - mean) * rsqrtf(fmaxf(var, 0.f) + LNEPS) * g[d] + bb[d];
  out_emb[((size_t)b * KK + k) * 256 + d] = o;
  if (d == 0) out_mask[b * KK + k] = (c > 0) ? 1.f : 0.f;
  __syncthreads();   // smem reused by next strided iteration
}

// ===================== mega-kernel (plain launch, hang-proof barriers) =====================
struct MegaParams {
  const float* x; const int* src; const int* dst; const int* mask; const float* sfeat;
  const float* Wi0; const float* Wo0; const float* bi0; const float* bo0;
  const float* Wi; const float* Wo; const float* bi; const float* bo;
  const float* ln_g; const float* ln_b; const float* fbn_g; const float* fbn_b;
  int* deg; int* bar; int* row_ptr; int* cursor; float* dinv; int* fid; float* rlpart;
  int2* epk; ushort_t* BT0; ushort_t* BTw; ushort_t* agg0b; ushort_t* agg2b;
  ushort_t* hbuf; float* out_emb; float* out_mask; float* out_reg;
};

__global__ __launch_bounds__(256, 4) void mega_kernel(MegaParams P) {
  __shared__ __align__(16) char smem[GEMM_SMEM];
  int t = threadIdx.x;
  int bid = blockIdx.x;
  int gsz = gridDim.x;
  int gid = bid * 256 + t;
  int gstride = gsz * 256;
  int wid = t >> 6, lane = t & 63;
  int gw = bid * 4 + wid, nw = gsz * 4;
  int* bcnt = P.bar;
  int* bep  = P.bar + 16;
  int eb = 0;

  // P0: degree count + fid + weight prep + regloss partials (deg zeroed by host memset)
  for (int e = gid; e < EE; e += gstride) atomicAdd(&P.deg[P.dst[e]], 1);
  for (int n = gid; n < NN; n += gstride) {
    int k = 0;
    #pragma unroll
    for (int j = 0; j < KK; j++) if (P.sfeat[n * KK + j] > 0.5f) k = j;
    P.fid[n] = k;
  }
  for (int wp = bid; wp < 288; wp += gsz) {
    if (wp < 96)       wprep_body(wp, P.Wi, P.Wo, P.BTw, smem);
    else if (wp < 224) bt0_body(wp, P.Wi0, P.Wo0, P.BT0);
    else               regloss_body(wp - 224, P.Wo0, P.bo0, P.Wo, P.bo, P.rlpart, smem);
  }
  gridbar(bcnt, bep, gsz, ++eb);

  // P1: scan (block 0 only)
  if (bid == 0) scan_body(P.deg, P.dinv, P.row_ptr, P.cursor, smem);
  gridbar(bcnt, bep, gsz, ++eb);

  // P2: bucket edges into CSR
  for (int e = gid; e < EE; e += gstride) {
    int sn = P.src[e], dn = P.dst[e];
    int p = atomicAdd(&P.cursor[dn], 1);
    P.epk[p] = make_int2(sn | (P.mask[e] ? (int)0x80000000 : 0),
                         __float_as_int(P.dinv[sn] * P.dinv[dn]));
  }
  gridbar(bcnt, bep, gsz, ++eb);

  // P3: layer-0 aggregation (wave per node, grid-strided)
  for (int n = gw; n < NN; n += nw)
    agg0_node(P.x, P.epk, P.row_ptr[n], P.row_ptr[n + 1], lane, P.agg0b + (size_t)n * 64);
  gridbar(bcnt, bep, gsz, ++eb);

  // P4: layer-0 GEMM + LN + ReLU (32-row tiles, grid-strided)
  for (int tile = bid; tile < NN / 32; tile += gsz)
    gemm_block<128>(P.agg0b, P.BT0, P.bi0, P.bo0, P.ln_g, P.ln_b, P.hbuf, tile * 32, smem);
  gridbar(bcnt, bep, gsz, ++eb);

  // layers 1..3
  for (int l = 0; l < LL - 1; l++) {
    for (int n = gw; n < NN; n += nw)
      agg_node(P.hbuf, P.epk, P.row_ptr, n, lane, P.agg2b + (size_t)n * 512);
    gridbar(bcnt, bep, gsz, ++eb);
    for (int tile = bid; tile < NN / 32; tile += gsz)
      gemm_block<1024>(P.agg2b, P.BTw + (size_t)l * 262144,
                       P.bi + l * 256, P.bo + l * 256,
                       P.ln_g + (l + 1) * 256, P.ln_b + (l + 1) * 256,
                       P.hbuf, tile * 32, smem);
    gridbar(bcnt, bep, gsz, ++eb);
  }

  // P7: fragment pooling + regloss final
  for (int fb = bid; fb < BGR * KK; fb += gsz)
    frag_block(P.hbuf, P.fid, P.fbn_g, P.fbn_b, P.out_emb, P.out_mask, fb >> 4, fb & 15, smem);
  if (bid == 0 && t < 64) {
    float sv = P.rlpart[t];
    #pragma unroll
    for (int off = 32; off > 0; off >>= 1) sv += __shfl_down(sv, off);
    if (t == 0) P.out_reg[0] = sv;
  }
}

// ---------------- launch ----------------
static inline size_t align256(size_t x) { return (x + 255) & ~(size_t)255; }

extern "C" void kernel_launch(void* const* d_in, const int* in_sizes, int n_in,
                              void* d_out, int out_size, void* d_ws, size_t ws_size,
                              hipStream_t stream) {
  const float* x      = (const float*)d_in[0];
  const int*   ei     = (const int*)d_in[1];
  const int*   mask   = (const int*)d_in[2];
  const float* s      = (const float*)d_in[3];
  const float* W_in0  = (const float*)d_in[5];
  const float* W_out0 = (const float*)d_in[6];
  const float* b_in0  = (const float*)d_in[7];
  const float* b_out0 = (const float*)d_in[8];
  const float* W_in   = (const float*)d_in[9];
  const float* W_out  = (const float*)d_in[10];
  const float* b_in   = (const float*)d_in[11];
  const float* b_out  = (const float*)d_in[12];
  const float* ln_g   = (const float*)d_in[13];
  const float* ln_b   = (const float*)d_in[14];
  const float* fbn_g  = (const float*)d_in[15];
  const float* fbn_b  = (const float*)d_in[16];

  const int* src = ei;
  const int* dst = ei + EE;

  char* w = (char*)d_ws;
  int*      deg     = (int*)w;      w += align256((size_t)NN * 4);
  int*      bar     = (int*)w;      w += 256;                       // barrier cnt/epoch
  int*      row_ptr = (int*)w;      w += align256((size_t)(NN + 1) * 4);
  int*      cursor  = (int*)w;      w += align256((size_t)NN * 4);
  float*    dinv    = (float*)w;    w += align256((size_t)NN * 4);
  int*      fid     = (int*)w;      w += align256((size_t)NN * 4);
  float*    rlpart  = (float*)w;    w += align256((size_t)64 * 4);
  int2*     epk     = (int2*)w;     w += align256((size_t)EE * 8);
  ushort_t* BT0     = (ushort_t*)w; w += align256((size_t)256 * 128 * 2);
  ushort_t* BTw     = (ushort_t*)w; w += align256((size_t)3 * 256 * 1024 * 2);
  ushort_t* agg0b   = (ushort_t*)w; w += align256((size_t)NN * 64 * 2);
  ushort_t* agg2b   = (ushort_t*)w; w += align256((size_t)NN * 512 * 2);
  ushort_t* hbuf    = (ushort_t*)w; w += align256((size_t)NN * 256 * 2);

  float* out_emb  = (float*)d_out;
  float* out_mask = out_emb + (size_t)BGR * KK * DD;
  float* out_reg  = out_emb + (size_t)out_size - 1;

  // zero deg + barrier words (deg and bar are contiguous: NN*4 + 256 bytes)
  hipMemsetAsync(deg, 0, (size_t)NN * 4 + 256, stream);

  MegaParams P;
  P.x = x; P.src = src; P.dst = dst; P.mask = mask; P.sfeat = s;
  P.Wi0 = W_in0; P.Wo0 = W_out0; P.bi0 = b_in0; P.bo0 = b_out0;
  P.Wi = W_in; P.Wo = W_out; P.bi = b_in; P.bo = b_out;
  P.ln_g = ln_g; P.ln_b = ln_b; P.fbn_g = fbn_g; P.fbn_b = fbn_b;
  P.deg = deg; P.bar = bar; P.row_ptr = row_ptr; P.cursor = cursor; P.dinv = dinv;
  P.fid = fid; P.rlpart = rlpart; P.epk = epk; P.BT0 = BT0; P.BTw = BTw;
  P.agg0b = agg0b; P.agg2b = agg2b; P.hbuf = hbuf;
  P.out_emb = out_emb; P.out_mask = out_mask; P.out_reg = out_reg;

  mega_kernel<<<GRID_BLKS, 256, 0, stream>>>(P);
}

// Round 7
// 1030.215 us; speedup vs baseline: 2.9046x; 2.9046x over previous
//
#include <hip/hip_runtime.h>

#define NN   10240
#define EE   320000
#define BGR  64
#define NPG  160
#define KK   16
#define DINF 25
#define DD   256
#define LL   4
#define LNEPS 1e-5f

#define GRID_BLKS 768   // 3 blocks/CU co-resident (proven in round 6)

typedef unsigned short ushort_t;
typedef __attribute__((ext_vector_type(8))) short s8v;
typedef __attribute__((ext_vector_type(4))) float f4v;

__device__ __forceinline__ float bf2f(ushort_t u) {
  union { unsigned u; float f; } a; a.u = ((unsigned)u) << 16; return a.f;
}
__device__ __forceinline__ ushort_t f2bf(float f) {
  union { float f; unsigned u; } a; a.f = f;
  unsigned r = (a.u + 0x7fffu + ((a.u >> 16) & 1u)) >> 16;   // RNE
  return (ushort_t)r;
}

// async global->LDS DMA, 16B per lane, dest = wave-uniform base + lane*16
__device__ __forceinline__ void gld16(const void* g, void* l) {
  __builtin_amdgcn_global_load_lds(
      (const __attribute__((address_space(1))) unsigned int*)g,
      (__attribute__((address_space(3))) unsigned int*)l, 16, 0, 0);
}

// ---------------- grid barrier v2: monotonic counter, RELAXED spin ----------------
// Round-6 post-mortem: ACQUIRE loads in the spin emit buffer_inv (full L1+L2
// invalidate) EVERY POLL -> 250us/barrier cache storm. Fix: exactly ONE release
// fence (wbl2) before arrival and ONE acquire fence (inv) after exit per block;
// spin is relaxed (L3-side load, no cache maintenance). Monotonic target = nb*epoch
// needs no reset. Escape hatch keeps it hang-proof.
__device__ __forceinline__ void gridbar(int* cnt, int nb, int et) {
  __syncthreads();
  if (threadIdx.x == 0) {
    __builtin_amdgcn_fence(__ATOMIC_RELEASE, "agent");   // one wbl2: publish my writes
    __hip_atomic_fetch_add(cnt, 1, __ATOMIC_RELAXED, __HIP_MEMORY_SCOPE_AGENT);
    int target = nb * et;
    int spins = 0;
    while (__hip_atomic_load(cnt, __ATOMIC_RELAXED, __HIP_MEMORY_SCOPE_AGENT) < target) {
      __builtin_amdgcn_s_sleep(2);
      if (++spins > (1 << 21)) break;                    // ~0.5s escape: never hang
    }
    __builtin_amdgcn_fence(__ATOMIC_ACQUIRE, "agent");   // one inv: see others' writes
  }
  __syncthreads();
}

// ---------------- block reduce (256 threads = 4 waves) ----------------
__device__ __forceinline__ float2 block_reduce2(float a, float b, float* red) {
  __syncthreads();
  #pragma unroll
  for (int off = 32; off > 0; off >>= 1) {
    a += __shfl_down(a, off);
    b += __shfl_down(b, off);
  }
  int lane = threadIdx.x & 63;
  int wid  = threadIdx.x >> 6;
  if (lane == 0) { red[wid * 2] = a; red[wid * 2 + 1] = b; }
  __syncthreads();
  float sa = red[0] + red[2] + red[4] + red[6];
  float sb = red[1] + red[3] + red[5] + red[7];
  return make_float2(sa, sb);
}

// ================= phase bodies (identical math to the verified 275us build) ==========

// weight transpose + hi/lo split for layers 1-3; wp in [0,96)
__device__ __forceinline__ void wprep_body(int wp, const float* __restrict__ Wi,
                                           const float* __restrict__ Wo,
                                           ushort_t* __restrict__ BT, char* smem) {
  int t = threadIdx.x;
  float (*tile)[65] = (float (*)[65])smem;     // 64x65 floats = 16640 B
  int l = wp >> 5, rem = wp & 31;
  int kb = rem >> 2, nb = rem & 3;
  int k0 = kb * 64, n0 = nb * 64;
  const float* Wl = (k0 < 256) ? (Wi + (size_t)l * 65536 + (size_t)k0 * 256)
                               : (Wo + (size_t)l * 65536 + (size_t)(k0 - 256) * 256);
  #pragma unroll
  for (int p = 0; p < 4; p++) {
    int ks = p * 16 + (t >> 4);
    int n  = (t & 15) * 4;
    float4 v = *(const float4*)&Wl[(size_t)ks * 256 + n0 + n];
    tile[ks][n] = v.x; tile[ks][n + 1] = v.y; tile[ks][n + 2] = v.z; tile[ks][n + 3] = v.w;
  }
  __syncthreads();
  ushort_t* BTl = BT + (size_t)l * 262144;
  #pragma unroll
  for (int p = 0; p < 2; p++) {
    int n  = p * 32 + (t >> 3);
    int kk = (t & 7) * 8;
    ushort_t hi[8], lo[8];
    #pragma unroll
    for (int j = 0; j < 8; j++) {
      float v = tile[kk + j][n];
      hi[j] = f2bf(v);
      lo[j] = f2bf(v - bf2f(hi[j]));
    }
    *(s8v*)&BTl[(size_t)(n0 + n) * 1024 + k0 + kk]       = *(const s8v*)hi;
    *(s8v*)&BTl[(size_t)(n0 + n) * 1024 + 512 + k0 + kk] = *(const s8v*)lo;
  }
  __syncthreads();
}

// layer-0 weight prep; wp in [96,224)
__device__ __forceinline__ void bt0_body(int wp, const float* __restrict__ Wi0,
                                         const float* __restrict__ Wo0,
                                         ushort_t* __restrict__ BT0) {
  int idx = (wp - 96) * 256 + threadIdx.x;   // n*128 + k
  int n = idx >> 7, k = idx & 127;
  int ks = k & 63;
  float v = 0.f;
  if (ks < DINF) v = Wi0[ks * 256 + n];
  else if (ks < 2 * DINF) v = Wo0[(ks - DINF) * 256 + n];
  ushort_t hi = f2bf(v);
  BT0[idx] = (k < 64) ? hi : f2bf(v - bf2f(hi));
}

// regloss partials; rb in [0,64)
__device__ __forceinline__ void regloss_body(int rb, const float* __restrict__ Wo0,
                                             const float* __restrict__ b_out0,
                                             const float* __restrict__ Wo,
                                             const float* __restrict__ b_out,
                                             float* __restrict__ partials, char* smem) {
  int t = threadIdx.x;
  int tid = rb * 256 + t;
  int stride = 64 * 256;
  float sum = 0.f;
  for (int i = tid; i < DINF * DD; i += stride)          sum += fabsf(Wo0[i]);
  for (int i = tid; i < DD; i += stride)                 sum += fabsf(b_out0[i]);
  for (int i = tid; i < (LL - 1) * DD * DD; i += stride) sum += fabsf(Wo[i]);
  for (int i = tid; i < (LL - 1) * DD; i += stride)      sum += fabsf(b_out[i]);
  float* red = (float*)smem;
  float2 ss = block_reduce2(sum, 0.f, red);
  if (t == 0) partials[rb] = ss.x;
}

// single-block full scan: deg -> dinv + row_ptr + cursor (256 thr x 40 nodes)
__device__ __forceinline__ void scan_body(const int* __restrict__ deg,
                                          float* __restrict__ dinv,
                                          int* __restrict__ row_ptr,
                                          int* __restrict__ cursor, char* smem) {
  int t = threadIdx.x;
  int base = t * 40;
  int dd[40];
  int sum = 0;
  #pragma unroll
  for (int i = 0; i < 10; i++) {
    int4 d4 = *(const int4*)&deg[base + i * 4];
    dd[i * 4] = d4.x; dd[i * 4 + 1] = d4.y; dd[i * 4 + 2] = d4.z; dd[i * 4 + 3] = d4.w;
    sum += d4.x + d4.y + d4.z + d4.w;
  }
  int lane = t & 63, wid = t >> 6;
  int v = sum;
  #pragma unroll
  for (int off = 1; off < 64; off <<= 1) {
    int u = __shfl_up(v, off);
    if (lane >= off) v += u;
  }
  int* ws = (int*)smem;
  if (lane == 63) ws[wid] = v;
  __syncthreads();
  int woff = 0;
  #pragma unroll
  for (int p = 0; p < 4; p++) woff += (p < wid) ? ws[p] : 0;
  int rp = woff + v - sum;
  #pragma unroll
  for (int i = 0; i < 10; i++) {
    int4 rr; float4 dv;
    rr.x = rp; dv.x = rsqrtf((float)max(dd[i * 4], 1));     rp += dd[i * 4];
    rr.y = rp; dv.y = rsqrtf((float)max(dd[i * 4 + 1], 1)); rp += dd[i * 4 + 1];
    rr.z = rp; dv.z = rsqrtf((float)max(dd[i * 4 + 2], 1)); rp += dd[i * 4 + 2];
    rr.w = rp; dv.w = rsqrtf((float)max(dd[i * 4 + 3], 1)); rp += dd[i * 4 + 3];
    *(int4*)&row_ptr[base + i * 4] = rr;
    *(int4*)&cursor[base + i * 4]  = rr;
    *(float4*)&dinv[base + i * 4]  = dv;
  }
  if (t == 0) row_ptr[NN] = EE;
}

// layer-0 per-node aggregation (whole wave on one node)
__device__ __forceinline__ void agg0_node(const float* __restrict__ x,
                                          const int2* __restrict__ epk,
                                          int e0, int e1, int lane,
                                          ushort_t* __restrict__ out) {
  int half = lane >> 5;
  int ch = lane & 31;
  int chc = (ch < DINF) ? ch : 0;
  float accI = 0.f, accO = 0.f;
  for (int c0 = e0; c0 < e1; c0 += 64) {
    int cnt = min(64, e1 - c0);
    int2 my = (lane < cnt) ? epk[c0 + lane] : make_int2(0, 0);
    int i = half;
    for (; i + 6 < cnt; i += 8) {
      unsigned u[4]; float wt[4], vv[4];
      #pragma unroll
      for (int j = 0; j < 4; j++) {
        u[j]  = (unsigned)__shfl(my.x, i + 2 * j);
        wt[j] = __int_as_float(__shfl(my.y, i + 2 * j));
      }
      #pragma unroll
      for (int j = 0; j < 4; j++)
        vv[j] = x[(size_t)(u[j] & 0x7fffffffu) * DINF + chc];
      #pragma unroll
      for (int j = 0; j < 4; j++) {
        float wI = (u[j] >> 31) ? wt[j] : 0.f;  float wO = wt[j] - wI;
        accI = fmaf(vv[j], wI, accI); accO = fmaf(vv[j], wO, accO);
      }
    }
    for (; i < cnt; i += 2) {
      unsigned u = (unsigned)__shfl(my.x, i);
      float wt = __int_as_float(__shfl(my.y, i));
      float vv = x[(size_t)(u & 0x7fffffffu) * DINF + chc];
      float wI = (u >> 31) ? wt : 0.f;  float wO = wt - wI;
      accI = fmaf(vv, wI, accI); accO = fmaf(vv, wO, accO);
    }
  }
  accI += __shfl_xor(accI, 32);
  accO += __shfl_xor(accO, 32);
  if (half == 0) {
    if (ch < DINF) {
      out[ch]        = f2bf(accI);
      out[DINF + ch] = f2bf(accO);
    } else {
      int k = 2 * DINF + (ch - DINF) * 2;
      out[k] = 0;
      out[k + 1] = 0;
    }
  }
}

// layers 1-3 per-node aggregation (whole wave on one node, scalar metadata)
__device__ __forceinline__ void agg_node(const ushort_t* __restrict__ h,
                                         const int2* __restrict__ epk,
                                         const int* __restrict__ row_ptr,
                                         int n, int lane,
                                         ushort_t* __restrict__ out) {
  int coff = lane * 4;
  int e0 = __builtin_amdgcn_readfirstlane(row_ptr[n]);
  int e1 = __builtin_amdgcn_readfirstlane(row_ptr[n + 1]);
  float aI0 = 0.f, aI1 = 0.f, aI2 = 0.f, aI3 = 0.f;
  float aO0 = 0.f, aO1 = 0.f, aO2 = 0.f, aO3 = 0.f;
  int i = e0;
  for (; i + 8 <= e1; i += 8) {
    int2 e[8];
    #pragma unroll
    for (int j = 0; j < 8; j++) e[j] = epk[i + j];
    ushort4 v[8];
    #pragma unroll
    for (int j = 0; j < 8; j++)
      v[j] = *(const ushort4*)&h[(size_t)(unsigned)(e[j].x & 0x7fffffff) * 256u + coff];
    #pragma unroll
    for (int j = 0; j < 8; j++) {
      float wt = __int_as_float(e[j].y);
      float wI = (e[j].x < 0) ? wt : 0.f;  float wO = wt - wI;
      float f;
      f = bf2f(v[j].x); aI0 = fmaf(f, wI, aI0); aO0 = fmaf(f, wO, aO0);
      f = bf2f(v[j].y); aI1 = fmaf(f, wI, aI1); aO1 = fmaf(f, wO, aO1);
      f = bf2f(v[j].z); aI2 = fmaf(f, wI, aI2); aO2 = fmaf(f, wO, aO2);
      f = bf2f(v[j].w); aI3 = fmaf(f, wI, aI3); aO3 = fmaf(f, wO, aO3);
    }
  }
  for (; i < e1; i++) {
    int2 e = epk[i];
    ushort4 v = *(const ushort4*)&h[(size_t)(unsigned)(e.x & 0x7fffffff) * 256u + coff];
    float wt = __int_as_float(e.y);
    float wI = (e.x < 0) ? wt : 0.f;  float wO = wt - wI;
    float f;
    f = bf2f(v.x); aI0 = fmaf(f, wI, aI0); aO0 = fmaf(f, wO, aO0);
    f = bf2f(v.y); aI1 = fmaf(f, wI, aI1); aO1 = fmaf(f, wO, aO1);
    f = bf2f(v.z); aI2 = fmaf(f, wI, aI2); aO2 = fmaf(f, wO, aO2);
    f = bf2f(v.w); aI3 = fmaf(f, wI, aI3); aO3 = fmaf(f, wO, aO3);
  }
  ushort4 pI, pO;
  pI.x = f2bf(aI0); pI.y = f2bf(aI1); pI.z = f2bf(aI2); pI.w = f2bf(aI3);
  pO.x = f2bf(aO0); pO.y = f2bf(aO1); pO.z = f2bf(aO2); pO.w = f2bf(aO3);
  *(ushort4*)&out[coff]       = pI;
  *(ushort4*)&out[256 + coff] = pO;
}

// MFMA GEMM + bias + LayerNorm + ReLU for one 32-row tile.
// smem layout: As @0 (4096B), Bs @4096 (32768B), redS @36864, redQ @37376. total 37888.
#define GEMM_SMEM 37888
template <int KB>
__device__ __forceinline__ void gemm_block(const ushort_t* __restrict__ A,
                                           const ushort_t* __restrict__ BT,
                                           const float* __restrict__ bi,
                                           const float* __restrict__ bo,
                                           const float* __restrict__ g,
                                           const float* __restrict__ bb,
                                           ushort_t* __restrict__ hout,
                                           int m0, char* smem) {
  constexpr int AK = KB / 2;               // A row length (shorts)
  constexpr int ABR = AK * 2;              // A row bytes
  constexpr int BBR = KB * 2;              // BT row bytes
  ushort_t* As = (ushort_t*)smem;
  ushort_t* Bs = (ushort_t*)(smem + 4096);
  float (*redS)[4] = (float (*)[4])(smem + 36864);
  float (*redQ)[4] = (float (*)[4])(smem + 37376);
  int t = threadIdx.x;
  int w = t >> 6;
  int lane = t & 63;
  int q = lane >> 4, n16 = lane & 15;
  int sx = (n16 & 7) << 3;                 // read-side swizzle (short units)
  f4v acc[2][4];
  #pragma unroll
  for (int rt = 0; rt < 2; rt++)
    #pragma unroll
    for (int ct = 0; ct < 4; ct++) acc[rt][ct] = (f4v){0.f, 0.f, 0.f, 0.f};

  int srow   = lane >> 3;
  int sobyte = (lane & 7) * 16;
  int arow   = w * 8 + srow;
  size_t a_base = (size_t)(m0 + arow) * ABR
                + (size_t)((unsigned)sobyte ^ ((unsigned)(arow & 7) << 4));
  char* as_dst = (char*)As + w * 1024;
  char* bs_dst = (char*)Bs + w * 8192;

  for (int k0 = 0; k0 < KB; k0 += 64) {
    __syncthreads();                       // previous tile fully consumed
    gld16((const char*)A + a_base + (size_t)((k0 & (AK - 1)) * 2), as_dst);
    #pragma unroll
    for (int j = 0; j < 8; j++) {
      int brow = w * 64 + j * 8 + srow;
      gld16((const char*)BT + (size_t)brow * BBR + (size_t)(k0 * 2)
                + (size_t)((unsigned)sobyte ^ ((unsigned)(brow & 7) << 4)),
            bs_dst + j * 1024);
    }
    asm volatile("s_waitcnt vmcnt(0)" ::: "memory");
    __syncthreads();                       // tile ready
    #pragma unroll
    for (int kk = 0; kk < 2; kk++) {
      int ko = (kk * 32 + q * 8) ^ sx;
      s8v af0 = *(const s8v*)&As[n16 * 64 + ko];
      s8v af1 = *(const s8v*)&As[(16 + n16) * 64 + ko];
      #pragma unroll
      for (int ct = 0; ct < 4; ct++) {
        s8v bf = *(const s8v*)&Bs[(w * 64 + ct * 16 + n16) * 64 + ko];
        acc[0][ct] = __builtin_amdgcn_mfma_f32_16x16x32_bf16(af0, bf, acc[0][ct], 0, 0, 0);
        acc[1][ct] = __builtin_amdgcn_mfma_f32_16x16x32_bf16(af1, bf, acc[1][ct], 0, 0, 0);
      }
    }
  }

  float biv[4], gv[4], bbv[4];
  #pragma unroll
  for (int ct = 0; ct < 4; ct++) {
    int c = w * 64 + ct * 16 + n16;
    biv[ct] = bi[c] + bo[c];
    gv[ct]  = g[c];
    bbv[ct] = bb[c];
  }
  #pragma unroll
  for (int rt = 0; rt < 2; rt++)
    #pragma unroll
    for (int rg = 0; rg < 4; rg++) {
      float s = 0.f, ss = 0.f;
      #pragma unroll
      for (int ct = 0; ct < 4; ct++) {
        float v = acc[rt][ct][rg] + biv[ct];
        s += v; ss += v * v;
      }
      #pragma unroll
      for (int off = 1; off < 16; off <<= 1) {
        s  += __shfl_xor(s, off);
        ss += __shfl_xor(ss, off);
      }
      if (n16 == 0) {
        int row = rt * 16 + q * 4 + rg;
        redS[row][w] = s;
        redQ[row][w] = ss;
      }
    }
  __syncthreads();
  #pragma unroll
  for (int rt = 0; rt < 2; rt++)
    #pragma unroll
    for (int rg = 0; rg < 4; rg++) {
      int row = rt * 16 + q * 4 + rg;
      float mean = (redS[row][0] + redS[row][1] + redS[row][2] + redS[row][3]) * (1.f / 256.f);
      float var  = (redQ[row][0] + redQ[row][1] + redQ[row][2] + redQ[row][3]) * (1.f / 256.f)
                   - mean * mean;
      float rs = rsqrtf(fmaxf(var, 0.f) + LNEPS);
      #pragma unroll
      for (int ct = 0; ct < 4; ct++) {
        float v = acc[rt][ct][rg] + biv[ct];
        float o = fmaxf((v - mean) * rs * gv[ct] + bbv[ct], 0.f);
        hout[(size_t)(m0 + row) * 256 + w * 64 + ct * 16 + n16] = f2bf(o);
      }
    }
}

// fragment pooling + LN + mask for one (b,k).  smem: list @0 (640B), cnt @640, red @656.
__device__ __forceinline__ void frag_block(const ushort_t* __restrict__ h,
                                           const int* __restrict__ fid,
                                           const float* __restrict__ g,
                                           const float* __restrict__ bb,
                                           float* __restrict__ out_emb,
                                           float* __restrict__ out_mask,
                                           int b, int k, char* smem) {
  int d = threadIdx.x;
  int* list = (int*)smem;
  int* cntp = (int*)(smem + 640);
  float* red = (float*)(smem + 656);
  if (d == 0) *cntp = 0;
  __syncthreads();
  int base = b * NPG;
  if (d < NPG) {
    if (fid[base + d] == k) { int p = atomicAdd(cntp, 1); list[p] = d; }
  }
  __syncthreads();
  int c = *cntp;
  float acc = 0.f;
  int i = 0;
  for (; i + 4 <= c; i += 4) {
    int l0 = list[i], l1 = list[i + 1], l2 = list[i + 2], l3 = list[i + 3];
    float a0 = bf2f(h[(size_t)(base + l0) * 256 + d]);
    float a1 = bf2f(h[(size_t)(base + l1) * 256 + d]);
    float a2 = bf2f(h[(size_t)(base + l2) * 256 + d]);
    float a3 = bf2f(h[(size_t)(base + l3) * 256 + d]);
    acc += (a0 + a1) + (a2 + a3);
  }
  for (; i < c; i++) {
    acc += bf2f(h[(size_t)(base + list[i]) * 256 + d]);
  }
  float2 ss = block_reduce2(acc, acc * acc, red);
  float mean = ss.x * (1.f / 256.f);
  float var  = ss.y * (1.f / 256.f) - mean * mean;
  float o = (acc - mean) * rsqrtf(fmaxf(var, 0.f) + LNEPS) * g[d] + bb[d];
  out_emb[((size_t)b * KK + k) * 256 + d] = o;
  if (d == 0) out_mask[b * KK + k] = (c > 0) ? 1.f : 0.f;
  __syncthreads();   // smem reused by next strided iteration
}

// ===================== mega-kernel (plain launch, low-cost barriers) =====================
struct MegaParams {
  const float* x; const int* src; const int* dst; const int* mask; const float* sfeat;
  const float* Wi0; const float* Wo0; const float* bi0; const float* bo0;
  const float* Wi; const float* Wo; const float* bi; const float* bo;
  const float* ln_g; const float* ln_b; const float* fbn_g; const float* fbn_b;
  int* deg; int* bar; int* row_ptr; int* cursor; float* dinv; int* fid; float* rlpart;
  int2* epk; ushort_t* BT0; ushort_t* BTw; ushort_t* agg0b; ushort_t* agg2b;
  ushort_t* hbuf; float* out_emb; float* out_mask; float* out_reg;
};

__global__ __launch_bounds__(256, 4) void mega_kernel(MegaParams P) {
  __shared__ __align__(16) char smem[GEMM_SMEM];
  int t = threadIdx.x;
  int bid = blockIdx.x;
  int gsz = gridDim.x;
  int gid = bid * 256 + t;
  int gstride = gsz * 256;
  int wid = t >> 6, lane = t & 63;
  int gw = bid * 4 + wid, nw = gsz * 4;
  int* bcnt = P.bar;
  int eb = 0;

  // P0: degree count + fid + weight prep + regloss partials (deg zeroed by host memset)
  for (int e = gid; e < EE; e += gstride) atomicAdd(&P.deg[P.dst[e]], 1);
  for (int n = gid; n < NN; n += gstride) {
    int k = 0;
    #pragma unroll
    for (int j = 0; j < KK; j++) if (P.sfeat[n * KK + j] > 0.5f) k = j;
    P.fid[n] = k;
  }
  for (int wp = bid; wp < 288; wp += gsz) {
    if (wp < 96)       wprep_body(wp, P.Wi, P.Wo, P.BTw, smem);
    else if (wp < 224) bt0_body(wp, P.Wi0, P.Wo0, P.BT0);
    else               regloss_body(wp - 224, P.Wo0, P.bo0, P.Wo, P.bo, P.rlpart, smem);
  }
  gridbar(bcnt, gsz, ++eb);

  // P1: scan (block 0 only)
  if (bid == 0) scan_body(P.deg, P.dinv, P.row_ptr, P.cursor, smem);
  gridbar(bcnt, gsz, ++eb);

  // P2: bucket edges into CSR
  for (int e = gid; e < EE; e += gstride) {
    int sn = P.src[e], dn = P.dst[e];
    int p = atomicAdd(&P.cursor[dn], 1);
    P.epk[p] = make_int2(sn | (P.mask[e] ? (int)0x80000000 : 0),
                         __float_as_int(P.dinv[sn] * P.dinv[dn]));
  }
  gridbar(bcnt, gsz, ++eb);

  // P3: layer-0 aggregation (wave per node, grid-strided)
  for (int n = gw; n < NN; n += nw)
    agg0_node(P.x, P.epk, P.row_ptr[n], P.row_ptr[n + 1], lane, P.agg0b + (size_t)n * 64);
  gridbar(bcnt, gsz, ++eb);

  // P4: layer-0 GEMM + LN + ReLU (32-row tiles, grid-strided)
  for (int tile = bid; tile < NN / 32; tile += gsz)
    gemm_block<128>(P.agg0b, P.BT0, P.bi0, P.bo0, P.ln_g, P.ln_b, P.hbuf, tile * 32, smem);
  gridbar(bcnt, gsz, ++eb);

  // layers 1..3
  for (int l = 0; l < LL - 1; l++) {
    for (int n = gw; n < NN; n += nw)
      agg_node(P.hbuf, P.epk, P.row_ptr, n, lane, P.agg2b + (size_t)n * 512);
    gridbar(bcnt, gsz, ++eb);
    for (int tile = bid; tile < NN / 32; tile += gsz)
      gemm_block<1024>(P.agg2b, P.BTw + (size_t)l * 262144,
                       P.bi + l * 256, P.bo + l * 256,
                       P.ln_g + (l + 1) * 256, P.ln_b + (l + 1) * 256,
                       P.hbuf, tile * 32, smem);
    gridbar(bcnt, gsz, ++eb);
  }

  // P7: fragment pooling + regloss final
  for (int fb = bid; fb < BGR * KK; fb += gsz)
    frag_block(P.hbuf, P.fid, P.fbn_g, P.fbn_b, P.out_emb, P.out_mask, fb >> 4, fb & 15, smem);
  if (bid == 0 && t < 64) {
    float sv = P.rlpart[t];
    #pragma unroll
    for (int off = 32; off > 0; off >>= 1) sv += __shfl_down(sv, off);
    if (t == 0) P.out_reg[0] = sv;
  }
}

// ---------------- launch ----------------
static inline size_t align256(size_t x) { return (x + 255) & ~(size_t)255; }

extern "C" void kernel_launch(void* const* d_in, const int* in_sizes, int n_in,
                              void* d_out, int out_size, void* d_ws, size_t ws_size,
                              hipStream_t stream) {
  const float* x      = (const float*)d_in[0];
  const int*   ei     = (const int*)d_in[1];
  const int*   mask   = (const int*)d_in[2];
  const float* s      = (const float*)d_in[3];
  const float* W_in0  = (const float*)d_in[5];
  const float* W_out0 = (const float*)d_in[6];
  const float* b_in0  = (const float*)d_in[7];
  const float* b_out0 = (const float*)d_in[8];
  const float* W_in   = (const float*)d_in[9];
  const float* W_out  = (const float*)d_in[10];
  const float* b_in   = (const float*)d_in[11];
  const float* b_out  = (const float*)d_in[12];
  const float* ln_g   = (const float*)d_in[13];
  const float* ln_b   = (const float*)d_in[14];
  const float* fbn_g  = (const float*)d_in[15];
  const float* fbn_b  = (const float*)d_in[16];

  const int* src = ei;
  const int* dst = ei + EE;

  char* w = (char*)d_ws;
  int*      deg     = (int*)w;      w += align256((size_t)NN * 4);
  int*      bar     = (int*)w;      w += 256;                       // barrier counter
  int*      row_ptr = (int*)w;      w += align256((size_t)(NN + 1) * 4);
  int*      cursor  = (int*)w;      w += align256((size_t)NN * 4);
  float*    dinv    = (float*)w;    w += align256((size_t)NN * 4);
  int*      fid     = (int*)w;      w += align256((size_t)NN * 4);
  float*    rlpart  = (float*)w;    w += align256((size_t)64 * 4);
  int2*     epk     = (int2*)w;     w += align256((size_t)EE * 8);
  ushort_t* BT0     = (ushort_t*)w; w += align256((size_t)256 * 128 * 2);
  ushort_t* BTw     = (ushort_t*)w; w += align256((size_t)3 * 256 * 1024 * 2);
  ushort_t* agg0b   = (ushort_t*)w; w += align256((size_t)NN * 64 * 2);
  ushort_t* agg2b   = (ushort_t*)w; w += align256((size_t)NN * 512 * 2);
  ushort_t* hbuf    = (ushort_t*)w; w += align256((size_t)NN * 256 * 2);

  float* out_emb  = (float*)d_out;
  float* out_mask = out_emb + (size_t)BGR * KK * DD;
  float* out_reg  = out_emb + (size_t)out_size - 1;

  // zero deg + barrier counter (contiguous: NN*4 + 256 bytes)
  hipMemsetAsync(deg, 0, (size_t)NN * 4 + 256, stream);

  MegaParams P;
  P.x = x; P.src = src; P.dst = dst; P.mask = mask; P.sfeat = s;
  P.Wi0 = W_in0; P.Wo0 = W_out0; P.bi0 = b_in0; P.bo0 = b_out0;
  P.Wi = W_in; P.Wo = W_out; P.bi = b_in; P.bo = b_out;
  P.ln_g = ln_g; P.ln_b = ln_b; P.fbn_g = fbn_g; P.fbn_b = fbn_b;
  P.deg = deg; P.bar = bar; P.row_ptr = row_ptr; P.cursor = cursor; P.dinv = dinv;
  P.fid = fid; P.rlpart = rlpart; P.epk = epk; P.BT0 = BT0; P.BTw = BTw;
  P.agg0b = agg0b; P.agg2b = agg2b; P.hbuf = hbuf;
  P.out_emb = out_emb; P.out_mask = out_mask; P.out_reg = out_reg;

  mega_kernel<<<GRID_BLKS, 256, 0, stream>>>(P);
}

// Round 8
// 508.208 us; speedup vs baseline: 5.8880x; 2.0272x over previous
//
#include <hip/hip_runtime.h>

#define NN   10240
#define EE   320000
#define BGR  64
#define NPG  160
#define KK   16
#define DINF 25
#define DD   256
#define LL   4
#define LNEPS 1e-5f

typedef unsigned short ushort_t;
typedef unsigned long long ull;
typedef __attribute__((ext_vector_type(8))) short s8v;
typedef __attribute__((ext_vector_type(4))) float f4v;

__device__ __forceinline__ float bf2f(ushort_t u) {
  union { unsigned u; float f; } a; a.u = ((unsigned)u) << 16; return a.f;
}
__device__ __forceinline__ ushort_t f2bf(float f) {
  union { float f; unsigned u; } a; a.f = f;
  unsigned r = (a.u + 0x7fffu + ((a.u >> 16) & 1u)) >> 16;   // RNE
  return (ushort_t)r;
}

// agent-scope relaxed atomics: write-through/read-at L3 (device coherence point).
// No fences, no L2 flush storms (round-6/7 lesson). Used ONLY on producer->consumer
// handoff data within a dispatch; everything else stays plain (CP flushes boundaries).
__device__ __forceinline__ void ast64(void* p, ull v) {
  __hip_atomic_store((ull*)p, v, __ATOMIC_RELAXED, __HIP_MEMORY_SCOPE_AGENT);
}
__device__ __forceinline__ ull ald64(const void* p) {
  return __hip_atomic_load((const ull*)p, __ATOMIC_RELAXED, __HIP_MEMORY_SCOPE_AGENT);
}
__device__ __forceinline__ void ast32(int* p, int v) {
  __hip_atomic_store(p, v, __ATOMIC_RELAXED, __HIP_MEMORY_SCOPE_AGENT);
}
__device__ __forceinline__ int ald32(const int* p) {
  return __hip_atomic_load(p, __ATOMIC_RELAXED, __HIP_MEMORY_SCOPE_AGENT);
}

// async global->LDS DMA, 16B per lane, dest = wave-uniform base + lane*16
__device__ __forceinline__ void gld16(const void* g, void* l) {
  __builtin_amdgcn_global_load_lds(
      (const __attribute__((address_space(1))) unsigned int*)g,
      (__attribute__((address_space(3))) unsigned int*)l, 16, 0, 0);
}

// ---------------- block reduce (256 threads = 4 waves) ----------------
__device__ __forceinline__ float2 block_reduce2(float a, float b, float* red) {
  __syncthreads();
  #pragma unroll
  for (int off = 32; off > 0; off >>= 1) {
    a += __shfl_down(a, off);
    b += __shfl_down(b, off);
  }
  int lane = threadIdx.x & 63;
  int wid  = threadIdx.x >> 6;
  if (lane == 0) { red[wid * 2] = a; red[wid * 2 + 1] = b; }
  __syncthreads();
  float sa = red[0] + red[2] + red[4] + red[6];
  float sb = red[1] + red[3] + red[5] + red[7];
  return make_float2(sa, sb);
}

// ---------------- setup (merged): degfid + weight prep + regloss partials ----------------
__global__ __launch_bounds__(256) void setup_kernel(const int* __restrict__ dst,
                                                    const float* __restrict__ s,
                                                    const float* __restrict__ Wi,
                                                    const float* __restrict__ Wo,
                                                    const float* __restrict__ Wi0,
                                                    const float* __restrict__ Wo0,
                                                    const float* __restrict__ b_out0,
                                                    const float* __restrict__ b_out,
                                                    int* __restrict__ deg,
                                                    int* __restrict__ fid,
                                                    ushort_t* __restrict__ BT,
                                                    ushort_t* __restrict__ BT0,
                                                    float* __restrict__ partials) {
  int bid0 = blockIdx.x;
  int t = threadIdx.x;
  if (bid0 < 1250) {
    int e = bid0 * 256 + t;
    if (e < EE) atomicAdd(&deg[dst[e]], 1);
    if (e < NN) {
      int k = 0;
      #pragma unroll
      for (int j = 0; j < KK; j++) if (s[e * KK + j] > 0.5f) k = j;
      fid[e] = k;
    }
    return;
  }
  int bid = bid0 - 1250;
  if (bid < 96) {
    int l = bid >> 5, rem = bid & 31;
    int kb = rem >> 2, nb = rem & 3;
    int k0 = kb * 64, n0 = nb * 64;
    __shared__ float tile[64][65];
    const float* Wl = (k0 < 256) ? (Wi + (size_t)l * 65536 + (size_t)k0 * 256)
                                 : (Wo + (size_t)l * 65536 + (size_t)(k0 - 256) * 256);
    #pragma unroll
    for (int p = 0; p < 4; p++) {
      int ks = p * 16 + (t >> 4);
      int n  = (t & 15) * 4;
      float4 v = *(const float4*)&Wl[(size_t)ks * 256 + n0 + n];
      tile[ks][n] = v.x; tile[ks][n + 1] = v.y; tile[ks][n + 2] = v.z; tile[ks][n + 3] = v.w;
    }
    __syncthreads();
    ushort_t* BTl = BT + (size_t)l * 262144;
    #pragma unroll
    for (int p = 0; p < 2; p++) {
      int n  = p * 32 + (t >> 3);
      int kk = (t & 7) * 8;
      ushort_t hi[8], lo[8];
      #pragma unroll
      for (int j = 0; j < 8; j++) {
        float v = tile[kk + j][n];
        hi[j] = f2bf(v);
        lo[j] = f2bf(v - bf2f(hi[j]));
      }
      *(s8v*)&BTl[(size_t)(n0 + n) * 1024 + k0 + kk]       = *(const s8v*)hi;
      *(s8v*)&BTl[(size_t)(n0 + n) * 1024 + 512 + k0 + kk] = *(const s8v*)lo;
    }
  } else if (bid < 224) {
    int idx = (bid - 96) * 256 + t;   // n*128 + k
    int n = idx >> 7, k = idx & 127;
    int ks = k & 63;
    float v = 0.f;
    if (ks < DINF) v = Wi0[ks * 256 + n];
    else if (ks < 2 * DINF) v = Wo0[(ks - DINF) * 256 + n];
    ushort_t hi = f2bf(v);
    BT0[idx] = (k < 64) ? hi : f2bf(v - bf2f(hi));
  } else {
    int rb = bid - 224;               // 0..63
    int tid = rb * 256 + t;
    int stride = 64 * 256;
    float sum = 0.f;
    for (int i = tid; i < DINF * DD; i += stride)          sum += fabsf(Wo0[i]);
    for (int i = tid; i < DD; i += stride)                 sum += fabsf(b_out0[i]);
    for (int i = tid; i < (LL - 1) * DD * DD; i += stride) sum += fabsf(Wo[i]);
    for (int i = tid; i < (LL - 1) * DD; i += stride)      sum += fabsf(b_out[i]);
    __shared__ float red[8];
    float2 ss = block_reduce2(sum, 0.f, red);
    if (t == 0) partials[rb] = ss.x;
  }
}

// ---------------- bucket kernel with merged scan (block 0 scans, agent-visible) ------
__global__ __launch_bounds__(256) void bucket_kernel(const int* __restrict__ src,
                                                     const int* __restrict__ dst,
                                                     const int* __restrict__ mask,
                                                     const int* __restrict__ deg,
                                                     float* __restrict__ dinv,
                                                     int* __restrict__ row_ptr,
                                                     int* __restrict__ cursor,
                                                     int2* __restrict__ epk,
                                                     int* __restrict__ sflag) {
  int t = threadIdx.x;
  if (blockIdx.x == 0) {
    // full scan: 256 threads x 40 nodes, serial prefix + block scan.
    __shared__ int ws[4];
    int base = t * 40;
    int dd[40];
    int sum = 0;
    #pragma unroll
    for (int i = 0; i < 10; i++) {
      int4 d4 = *(const int4*)&deg[base + i * 4];
      dd[i * 4] = d4.x; dd[i * 4 + 1] = d4.y; dd[i * 4 + 2] = d4.z; dd[i * 4 + 3] = d4.w;
      sum += d4.x + d4.y + d4.z + d4.w;
    }
    int lane = t & 63, wid = t >> 6;
    int v = sum;
    #pragma unroll
    for (int off = 1; off < 64; off <<= 1) {
      int u = __shfl_up(v, off);
      if (lane >= off) v += u;
    }
    if (lane == 63) ws[wid] = v;
    __syncthreads();
    int woff = 0;
    #pragma unroll
    for (int p = 0; p < 4; p++) woff += (p < wid) ? ws[p] : 0;
    int rp = woff + v - sum;
    #pragma unroll
    for (int i = 0; i < 10; i++) {
      int r[4]; unsigned dv[4];
      #pragma unroll
      for (int j = 0; j < 4; j++) {
        r[j] = rp;
        dv[j] = __float_as_uint(rsqrtf((float)max(dd[i * 4 + j], 1)));
        rp += dd[i * 4 + j];
      }
      ull r01 = (unsigned)r[0] | ((ull)(unsigned)r[1] << 32);
      ull r23 = (unsigned)r[2] | ((ull)(unsigned)r[3] << 32);
      ull d01 = dv[0] | ((ull)dv[1] << 32);
      ull d23 = dv[2] | ((ull)dv[3] << 32);
      ast64(&row_ptr[base + i * 4], r01); ast64(&row_ptr[base + i * 4 + 2], r23);
      ast64(&cursor[base + i * 4], r01);  ast64(&cursor[base + i * 4 + 2], r23);
      ast64(&dinv[base + i * 4], d01);    ast64(&dinv[base + i * 4 + 2], d23);
    }
    if (t == 0) ast32(&row_ptr[NN], EE);
    asm volatile("s_waitcnt vmcnt(0)" ::: "memory");
    __syncthreads();
    if (t == 0) ast32(sflag, 1);
  } else {
    if (t == 0) {
      int spins = 0;
      while (ald32(sflag) == 0) {
        __builtin_amdgcn_s_sleep(2);
        if (++spins > (1 << 22)) break;    // hang-proof
      }
    }
    __syncthreads();
  }
  int e = blockIdx.x * 256 + t;
  if (e >= EE) return;
  int sn = src[e], dn = dst[e];
  float ds = __uint_as_float((unsigned)(ald64(&((const ull*)dinv)[0]) , 0));  // placeholder avoided
  // dinv via agent 32-bit loads (L3-fresh within this dispatch)
  float fs = __int_as_float(ald32((const int*)&dinv[sn]));
  float fd = __int_as_float(ald32((const int*)&dinv[dn]));
  (void)ds;
  int p = atomicAdd(&cursor[dn], 1);
  epk[p] = make_int2(sn | (mask[e] ? (int)0x80000000 : 0), __float_as_int(fs * fd));
}

// ---------------- layer-0 per-node aggregation -> agent-visible row ----------------
__device__ __forceinline__ void agg0_node(const float* __restrict__ x,
                                          const int2* __restrict__ epk,
                                          int e0, int e1, int lane,
                                          ushort_t* __restrict__ out) {
  int half = lane >> 5;
  int ch = lane & 31;
  int chc = (ch < DINF) ? ch : 0;
  float accI = 0.f, accO = 0.f;
  for (int c0 = e0; c0 < e1; c0 += 64) {
    int cnt = min(64, e1 - c0);
    int2 my = (lane < cnt) ? epk[c0 + lane] : make_int2(0, 0);
    int i = half;
    for (; i + 6 < cnt; i += 8) {
      unsigned u[4]; float wt[4], vv[4];
      #pragma unroll
      for (int j = 0; j < 4; j++) {
        u[j]  = (unsigned)__shfl(my.x, i + 2 * j);
        wt[j] = __int_as_float(__shfl(my.y, i + 2 * j));
      }
      #pragma unroll
      for (int j = 0; j < 4; j++)
        vv[j] = x[(size_t)(u[j] & 0x7fffffffu) * DINF + chc];
      #pragma unroll
      for (int j = 0; j < 4; j++) {
        float wI = (u[j] >> 31) ? wt[j] : 0.f;  float wO = wt[j] - wI;
        accI = fmaf(vv[j], wI, accI); accO = fmaf(vv[j], wO, accO);
      }
    }
    for (; i < cnt; i += 2) {
      unsigned u = (unsigned)__shfl(my.x, i);
      float wt = __int_as_float(__shfl(my.y, i));
      float vv = x[(size_t)(u & 0x7fffffffu) * DINF + chc];
      float wI = (u >> 31) ? wt : 0.f;  float wO = wt - wI;
      accI = fmaf(vv, wI, accI); accO = fmaf(vv, wO, accO);
    }
  }
  accI += __shfl_xor(accI, 32);
  accO += __shfl_xor(accO, 32);
  // pack row [I(25)|O(25)|zeros(14)] into 16 x 8B agent stores (lanes 0..15)
  ushort_t sv[4];
  #pragma unroll
  for (int j = 0; j < 4; j++) {
    int p = (lane & 15) * 4 + j;
    float vI = __shfl(accI, p & 31);
    float vO = __shfl(accO, (p - DINF) & 31);
    float v = (p < DINF) ? vI : ((p < 2 * DINF) ? vO : 0.f);
    sv[j] = f2bf(v);
  }
  if (lane < 16) {
    union { ushort_t s[4]; ull v; } u;
    u.s[0] = sv[0]; u.s[1] = sv[1]; u.s[2] = sv[2]; u.s[3] = sv[3];
    ast64((ull*)out + lane, u.v);
  }
}

// ---------------- layers 1-3 per-node aggregation -> agent-visible row ----------------
__device__ __forceinline__ void agg_node(const ushort_t* __restrict__ h,
                                         const int2* __restrict__ epk,
                                         const int* __restrict__ row_ptr,
                                         int n, int lane,
                                         ushort_t* __restrict__ out) {
  int coff = lane * 4;
  int e0 = __builtin_amdgcn_readfirstlane(row_ptr[n]);
  int e1 = __builtin_amdgcn_readfirstlane(row_ptr[n + 1]);
  float aI0 = 0.f, aI1 = 0.f, aI2 = 0.f, aI3 = 0.f;
  float aO0 = 0.f, aO1 = 0.f, aO2 = 0.f, aO3 = 0.f;
  int i = e0;
  for (; i + 8 <= e1; i += 8) {
    int2 e[8];
    #pragma unroll
    for (int j = 0; j < 8; j++) e[j] = epk[i + j];
    ushort4 v[8];
    #pragma unroll
    for (int j = 0; j < 8; j++)
      v[j] = *(const ushort4*)&h[(size_t)(unsigned)(e[j].x & 0x7fffffff) * 256u + coff];
    #pragma unroll
    for (int j = 0; j < 8; j++) {
      float wt = __int_as_float(e[j].y);
      float wI = (e[j].x < 0) ? wt : 0.f;  float wO = wt - wI;
      float f;
      f = bf2f(v[j].x); aI0 = fmaf(f, wI, aI0); aO0 = fmaf(f, wO, aO0);
      f = bf2f(v[j].y); aI1 = fmaf(f, wI, aI1); aO1 = fmaf(f, wO, aO1);
      f = bf2f(v[j].z); aI2 = fmaf(f, wI, aI2); aO2 = fmaf(f, wO, aO2);
      f = bf2f(v[j].w); aI3 = fmaf(f, wI, aI3); aO3 = fmaf(f, wO, aO3);
    }
  }
  for (; i < e1; i++) {
    int2 e = epk[i];
    ushort4 v = *(const ushort4*)&h[(size_t)(unsigned)(e.x & 0x7fffffff) * 256u + coff];
    float wt = __int_as_float(e.y);
    float wI = (e.x < 0) ? wt : 0.f;  float wO = wt - wI;
    float f;
    f = bf2f(v.x); aI0 = fmaf(f, wI, aI0); aO0 = fmaf(f, wO, aO0);
    f = bf2f(v.y); aI1 = fmaf(f, wI, aI1); aO1 = fmaf(f, wO, aO1);
    f = bf2f(v.z); aI2 = fmaf(f, wI, aI2); aO2 = fmaf(f, wO, aO2);
    f = bf2f(v.w); aI3 = fmaf(f, wI, aI3); aO3 = fmaf(f, wO, aO3);
  }
  union { ushort_t s[4]; ull v; } uI, uO;
  uI.s[0] = f2bf(aI0); uI.s[1] = f2bf(aI1); uI.s[2] = f2bf(aI2); uI.s[3] = f2bf(aI3);
  uO.s[0] = f2bf(aO0); uO.s[1] = f2bf(aO1); uO.s[2] = f2bf(aO2); uO.s[3] = f2bf(aO3);
  ast64(&out[coff], uI.v);
  ast64(&out[256 + coff], uO.v);
}

// ---------------- MFMA GEMM + bias + LN + ReLU; A read agent-scope (L3-fresh) --------
#define GEMM_SMEM 37888
template <int KB>
__device__ __forceinline__ void gemm_block(const ushort_t* __restrict__ A,
                                           const ushort_t* __restrict__ BT,
                                           const float* __restrict__ bi,
                                           const float* __restrict__ bo,
                                           const float* __restrict__ g,
                                           const float* __restrict__ bb,
                                           ushort_t* __restrict__ hout,
                                           int m0, char* smem) {
  constexpr int AK = KB / 2;
  constexpr int ABR = AK * 2;
  constexpr int BBR = KB * 2;
  ushort_t* As = (ushort_t*)smem;
  ushort_t* Bs = (ushort_t*)(smem + 4096);
  float (*redS)[4] = (float (*)[4])(smem + 36864);
  float (*redQ)[4] = (float (*)[4])(smem + 37376);
  int t = threadIdx.x;
  int w = t >> 6;
  int lane = t & 63;
  int q = lane >> 4, n16 = lane & 15;
  int sx = (n16 & 7) << 3;
  f4v acc[2][4];
  #pragma unroll
  for (int rt = 0; rt < 2; rt++)
    #pragma unroll
    for (int ct = 0; ct < 4; ct++) acc[rt][ct] = (f4v){0.f, 0.f, 0.f, 0.f};

  int srow   = lane >> 3;
  int sobyte = (lane & 7) * 16;
  int arow   = w * 8 + srow;
  size_t a_src = (size_t)(m0 + arow) * ABR + (size_t)sobyte;           // straight source
  int a_lds = w * 1024 + srow * 128 + (sobyte ^ ((arow & 7) << 4));    // swizzled dest
  char* bs_dst = (char*)Bs + w * 8192;

  for (int k0 = 0; k0 < KB; k0 += 64) {
    __syncthreads();                       // previous tile fully consumed
    size_t ak = a_src + (size_t)((k0 & (AK - 1)) * 2);
    ull a0 = ald64((const char*)A + ak);
    ull a1 = ald64((const char*)A + ak + 8);
    #pragma unroll
    for (int j = 0; j < 8; j++) {
      int brow = w * 64 + j * 8 + srow;
      gld16((const char*)BT + (size_t)brow * BBR + (size_t)(k0 * 2)
                + (size_t)((unsigned)sobyte ^ ((unsigned)(brow & 7) << 4)),
            bs_dst + j * 1024);
    }
    asm volatile("s_waitcnt vmcnt(0)" ::: "memory");
    *(ull*)((char*)As + a_lds)     = a0;
    *(ull*)((char*)As + a_lds + 8) = a1;
    __syncthreads();                       // tile ready (barrier drains lgkm)
    #pragma unroll
    for (int kk = 0; kk < 2; kk++) {
      int ko = (kk * 32 + q * 8) ^ sx;
      s8v af0 = *(const s8v*)&As[n16 * 64 + ko];
      s8v af1 = *(const s8v*)&As[(16 + n16) * 64 + ko];
      #pragma unroll
      for (int ct = 0; ct < 4; ct++) {
        s8v bf = *(const s8v*)&Bs[(w * 64 + ct * 16 + n16) * 64 + ko];
        acc[0][ct] = __builtin_amdgcn_mfma_f32_16x16x32_bf16(af0, bf, acc[0][ct], 0, 0, 0);
        acc[1][ct] = __builtin_amdgcn_mfma_f32_16x16x32_bf16(af1, bf, acc[1][ct], 0, 0, 0);
      }
    }
  }

  float biv[4], gv[4], bbv[4];
  #pragma unroll
  for (int ct = 0; ct < 4; ct++) {
    int c = w * 64 + ct * 16 + n16;
    biv[ct] = bi[c] + bo[c];
    gv[ct]  = g[c];
    bbv[ct] = bb[c];
  }
  #pragma unroll
  for (int rt = 0; rt < 2; rt++)
    #pragma unroll
    for (int rg = 0; rg < 4; rg++) {
      float s = 0.f, ss = 0.f;
      #pragma unroll
      for (int ct = 0; ct < 4; ct++) {
        float v = acc[rt][ct][rg] + biv[ct];
        s += v; ss += v * v;
      }
      #pragma unroll
      for (int off = 1; off < 16; off <<= 1) {
        s  += __shfl_xor(s, off);
        ss += __shfl_xor(ss, off);
      }
      if (n16 == 0) {
        int row = rt * 16 + q * 4 + rg;
        redS[row][w] = s;
        redQ[row][w] = ss;
      }
    }
  __syncthreads();
  #pragma unroll
  for (int rt = 0; rt < 2; rt++)
    #pragma unroll
    for (int rg = 0; rg < 4; rg++) {
      int row = rt * 16 + q * 4 + rg;
      float mean = (redS[row][0] + redS[row][1] + redS[row][2] + redS[row][3]) * (1.f / 256.f);
      float var  = (redQ[row][0] + redQ[row][1] + redQ[row][2] + redQ[row][3]) * (1.f / 256.f)
                   - mean * mean;
      float rs = rsqrtf(fmaxf(var, 0.f) + LNEPS);
      #pragma unroll
      for (int ct = 0; ct < 4; ct++) {
        float v = acc[rt][ct][rg] + biv[ct];
        float o = fmaxf((v - mean) * rs * gv[ct] + bbv[ct], 0.f);
        hout[(size_t)(m0 + row) * 256 + w * 64 + ct * 16 + n16] = f2bf(o);
      }
    }
}

// ---------------- fused layer: all blocks agg 4 nodes; blocks <320 then gemm --------
// Grid 2560. tile t <- agg blocks 8t..8t+7 (flag==8). Waiters(320) < capacity(1024
// @4 blocks/CU) and every block aggs before spinning -> deadlock-free.
template <int KB, bool L0>
__global__ __launch_bounds__(256, 4) void fused_layer(const float* __restrict__ x,
                                                      const ushort_t* __restrict__ hin,
                                                      const int2* __restrict__ epk,
                                                      const int* __restrict__ row_ptr,
                                                      ushort_t* __restrict__ aggb,
                                                      const ushort_t* __restrict__ BT,
                                                      const float* __restrict__ bi,
                                                      const float* __restrict__ bo,
                                                      const float* __restrict__ g,
                                                      const float* __restrict__ bb,
                                                      ushort_t* __restrict__ hout,
                                                      int* __restrict__ tflag) {
  __shared__ __align__(16) char smem[GEMM_SMEM];
  int t = threadIdx.x, bid = blockIdx.x;
  int lane = t & 63, wv = t >> 6;
  constexpr int ROWB = L0 ? 64 : 512;
  int n = bid * 4 + wv;
  if (L0) agg0_node(x, epk, row_ptr[n], row_ptr[n + 1], lane, aggb + (size_t)n * ROWB);
  else    agg_node(hin, epk, row_ptr, n, lane, aggb + (size_t)n * ROWB);
  asm volatile("s_waitcnt vmcnt(0)" ::: "memory");   // agent stores at L3
  __syncthreads();
  if (t == 0) atomicAdd(&tflag[bid >> 3], 1);        // device-scope RMW, after drain
  if (bid >= NN / 32) return;
  if (t == 0) {
    int spins = 0;
    while (ald32(&tflag[bid]) < 8) {
      __builtin_amdgcn_s_sleep(2);
      if (++spins > (1 << 22)) break;                // hang-proof
    }
  }
  __syncthreads();
  gemm_block<KB>(aggb, BT, bi, bo, g, bb, hout, bid * 32, smem);
}

// ---------------- fragment pooling + LN + mask; extra block finalizes regloss --------
__global__ __launch_bounds__(256) void frag_pool_kernel(const ushort_t* __restrict__ h,
                                                        const int* __restrict__ fid,
                                                        const float* __restrict__ g,
                                                        const float* __restrict__ bb,
                                                        const float* __restrict__ partials,
                                                        float* __restrict__ out_emb,
                                                        float* __restrict__ out_mask,
                                                        float* __restrict__ out_reg) {
  int d = threadIdx.x;
  if (blockIdx.x == BGR * KK) {
    if (d < 64) {
      float sv = partials[d];
      #pragma unroll
      for (int off = 32; off > 0; off >>= 1) sv += __shfl_down(sv, off);
      if (d == 0) out_reg[0] = sv;
    }
    return;
  }
  int b = blockIdx.x >> 4;
  int k = blockIdx.x & 15;
  __shared__ int list[NPG];
  __shared__ int cnt;
  __shared__ float red[8];
  if (d == 0) cnt = 0;
  __syncthreads();
  int base = b * NPG;
  if (d < NPG) {
    if (fid[base + d] == k) { int p = atomicAdd(&cnt, 1); list[p] = d; }
  }
  __syncthreads();
  int c = cnt;
  float acc = 0.f;
  int i = 0;
  for (; i + 4 <= c; i += 4) {
    int l0 = list[i], l1 = list[i + 1], l2 = list[i + 2], l3 = list[i + 3];
    float a0 = bf2f(h[(size_t)(base + l0) * 256 + d]);
    float a1 = bf2f(h[(size_t)(base + l1) * 256 + d]);
    float a2 = bf2f(h[(size_t)(base + l2) * 256 + d]);
    float a3 = bf2f(h[(size_t)(base + l3) * 256 + d]);
    acc += (a0 + a1) + (a2 + a3);
  }
  for (; i < c; i++) {
    acc += bf2f(h[(size_t)(base + list[i]) * 256 + d]);
  }
  float2 ss = block_reduce2(acc, acc * acc, red);
  float mean = ss.x * (1.f / 256.f);
  float var  = ss.y * (1.f / 256.f) - mean * mean;
  float o = (acc - mean) * rsqrtf(fmaxf(var, 0.f) + LNEPS) * g[d] + bb[d];
  out_emb[((size_t)b * KK + k) * 256 + d] = o;
  if (d == 0) out_mask[b * KK + k] = (c > 0) ? 1.f : 0.f;
}

// ---------------- launch ----------------
static inline size_t align256(size_t x) { return (x + 255) & ~(size_t)255; }

extern "C" void kernel_launch(void* const* d_in, const int* in_sizes, int n_in,
                              void* d_out, int out_size, void* d_ws, size_t ws_size,
                              hipStream_t stream) {
  const float* x      = (const float*)d_in[0];
  const int*   ei     = (const int*)d_in[1];
  const int*   mask   = (const int*)d_in[2];
  const float* s      = (const float*)d_in[3];
  const float* W_in0  = (const float*)d_in[5];
  const float* W_out0 = (const float*)d_in[6];
  const float* b_in0  = (const float*)d_in[7];
  const float* b_out0 = (const float*)d_in[8];
  const float* W_in   = (const float*)d_in[9];
  const float* W_out  = (const float*)d_in[10];
  const float* b_in   = (const float*)d_in[11];
  const float* b_out  = (const float*)d_in[12];
  const float* ln_g   = (const float*)d_in[13];
  const float* ln_b   = (const float*)d_in[14];
  const float* fbn_g  = (const float*)d_in[15];
  const float* fbn_b  = (const float*)d_in[16];

  const int* src = ei;
  const int* dst = ei + EE;

  char* w = (char*)d_ws;
  int*      deg     = (int*)w;      w += align256((size_t)NN * 4);        // 40960
  int*      bar     = (int*)w;      w += 8192;   // sflag @0, tflags @16+l*320
  int*      row_ptr = (int*)w;      w += align256((size_t)(NN + 1) * 4);
  int*      cursor  = (int*)w;      w += align256((size_t)NN * 4);
  float*    dinv    = (float*)w;    w += align256((size_t)NN * 4);
  int*      fid     = (int*)w;      w += align256((size_t)NN * 4);
  float*    rlpart  = (float*)w;    w += align256((size_t)64 * 4);
  int2*     epk     = (int2*)w;     w += align256((size_t)EE * 8);
  ushort_t* BT0     = (ushort_t*)w; w += align256((size_t)256 * 128 * 2);
  ushort_t* BTw     = (ushort_t*)w; w += align256((size_t)3 * 256 * 1024 * 2);
  ushort_t* agg0b   = (ushort_t*)w; w += align256((size_t)NN * 64 * 2);
  ushort_t* agg2b   = (ushort_t*)w; w += align256((size_t)NN * 512 * 2);
  ushort_t* hbufA   = (ushort_t*)w; w += align256((size_t)NN * 256 * 2);
  ushort_t* hbufB   = (ushort_t*)w; w += align256((size_t)NN * 256 * 2);

  float* out_emb  = (float*)d_out;
  float* out_mask = out_emb + (size_t)BGR * KK * DD;
  float* out_reg  = out_emb + (size_t)out_size - 1;

  // zero deg + flag region (contiguous)
  hipMemsetAsync(deg, 0, (size_t)align256((size_t)NN * 4) + 8192, stream);

  setup_kernel<<<1250 + 288, 256, 0, stream>>>(dst, s, W_in, W_out, W_in0, W_out0,
                                               b_out0, b_out, deg, fid, BTw, BT0, rlpart);
  bucket_kernel<<<(EE + 255) / 256, 256, 0, stream>>>(src, dst, mask, deg, dinv,
                                                      row_ptr, cursor, epk, bar);

  // fused layers: agg + per-tile-flag + gemm, 2560 blocks each
  fused_layer<128, true><<<NN / 4, 256, 0, stream>>>(x, nullptr, epk, row_ptr, agg0b,
                                                     BT0, b_in0, b_out0, ln_g, ln_b,
                                                     hbufA, bar + 16);
  fused_layer<1024, false><<<NN / 4, 256, 0, stream>>>(nullptr, hbufA, epk, row_ptr, agg2b,
                                                       BTw, b_in, b_out,
                                                       ln_g + 256, ln_b + 256,
                                                       hbufB, bar + 16 + 320);
  fused_layer<1024, false><<<NN / 4, 256, 0, stream>>>(nullptr, hbufB, epk, row_ptr, agg2b,
                                                       BTw + 262144, b_in + 256, b_out + 256,
                                                       ln_g + 512, ln_b + 512,
                                                       hbufA, bar + 16 + 640);
  fused_layer<1024, false><<<NN / 4, 256, 0, stream>>>(nullptr, hbufA, epk, row_ptr, agg2b,
                                                       BTw + 524288, b_in + 512, b_out + 512,
                                                       ln_g + 768, ln_b + 768,
                                                       hbufB, bar + 16 + 960);

  frag_pool_kernel<<<BGR * KK + 1, 256, 0, stream>>>(hbufB, fid, fbn_g, fbn_b, rlpart,
                                                     out_emb, out_mask, out_reg);
}

// Round 9
// 297.392 us; speedup vs baseline: 10.0619x; 1.7089x over previous
//
#include <hip/hip_runtime.h>

#define NN   10240
#define EE   320000
#define BGR  64
#define NPG  160
#define KK   16
#define DINF 25
#define DD   256
#define LL   4
#define LNEPS 1e-5f

typedef unsigned short ushort_t;
typedef unsigned long long ull;
typedef __attribute__((ext_vector_type(8))) short s8v;
typedef __attribute__((ext_vector_type(4))) float f4v;

__device__ __forceinline__ float bf2f(ushort_t u) {
  union { unsigned u; float f; } a; a.u = ((unsigned)u) << 16; return a.f;
}
__device__ __forceinline__ ushort_t f2bf(float f) {
  union { float f; unsigned u; } a; a.f = f;
  unsigned r = (a.u + 0x7fffu + ((a.u >> 16) & 1u)) >> 16;   // RNE
  return (ushort_t)r;
}

// agent-scope relaxed atomics (L3 coherence point) — used ONLY for the tiny
// scan->bucket handoff inside bucket_kernel (120 KB). Round-8 lesson: NEVER put
// bulk data on this path (uncached, ~5x slower than L2); round-6/7 lesson: never
// use acquire/release in spin loops (L2-flush storms).
__device__ __forceinline__ void ast64(void* p, ull v) {
  __hip_atomic_store((ull*)p, v, __ATOMIC_RELAXED, __HIP_MEMORY_SCOPE_AGENT);
}
__device__ __forceinline__ void ast32(int* p, int v) {
  __hip_atomic_store(p, v, __ATOMIC_RELAXED, __HIP_MEMORY_SCOPE_AGENT);
}
__device__ __forceinline__ int ald32(const int* p) {
  return __hip_atomic_load(p, __ATOMIC_RELAXED, __HIP_MEMORY_SCOPE_AGENT);
}

// async global->LDS DMA, 16B per lane, dest = wave-uniform base + lane*16
__device__ __forceinline__ void gld16(const void* g, void* l) {
  __builtin_amdgcn_global_load_lds(
      (const __attribute__((address_space(1))) unsigned int*)g,
      (__attribute__((address_space(3))) unsigned int*)l, 16, 0, 0);
}

// ---------------- block reduce (256 threads = 4 waves) ----------------
__device__ __forceinline__ float2 block_reduce2(float a, float b, float* red) {
  __syncthreads();
  #pragma unroll
  for (int off = 32; off > 0; off >>= 1) {
    a += __shfl_down(a, off);
    b += __shfl_down(b, off);
  }
  int lane = threadIdx.x & 63;
  int wid  = threadIdx.x >> 6;
  if (lane == 0) { red[wid * 2] = a; red[wid * 2 + 1] = b; }
  __syncthreads();
  float sa = red[0] + red[2] + red[4] + red[6];
  float sb = red[1] + red[3] + red[5] + red[7];
  return make_float2(sa, sb);
}

// ---------------- setup (merged): degfid + weight prep + regloss partials ----------------
__global__ __launch_bounds__(256) void setup_kernel(const int* __restrict__ dst,
                                                    const float* __restrict__ s,
                                                    const float* __restrict__ Wi,
                                                    const float* __restrict__ Wo,
                                                    const float* __restrict__ Wi0,
                                                    const float* __restrict__ Wo0,
                                                    const float* __restrict__ b_out0,
                                                    const float* __restrict__ b_out,
                                                    int* __restrict__ deg,
                                                    int* __restrict__ fid,
                                                    ushort_t* __restrict__ BT,
                                                    ushort_t* __restrict__ BT0,
                                                    float* __restrict__ partials) {
  int bid0 = blockIdx.x;
  int t = threadIdx.x;
  if (bid0 < 1250) {
    int e = bid0 * 256 + t;
    if (e < EE) atomicAdd(&deg[dst[e]], 1);
    if (e < NN) {
      int k = 0;
      #pragma unroll
      for (int j = 0; j < KK; j++) if (s[e * KK + j] > 0.5f) k = j;
      fid[e] = k;
    }
    return;
  }
  int bid = bid0 - 1250;
  if (bid < 96) {
    int l = bid >> 5, rem = bid & 31;
    int kb = rem >> 2, nb = rem & 3;
    int k0 = kb * 64, n0 = nb * 64;
    __shared__ float tile[64][65];
    const float* Wl = (k0 < 256) ? (Wi + (size_t)l * 65536 + (size_t)k0 * 256)
                                 : (Wo + (size_t)l * 65536 + (size_t)(k0 - 256) * 256);
    #pragma unroll
    for (int p = 0; p < 4; p++) {
      int ks = p * 16 + (t >> 4);
      int n  = (t & 15) * 4;
      float4 v = *(const float4*)&Wl[(size_t)ks * 256 + n0 + n];
      tile[ks][n] = v.x; tile[ks][n + 1] = v.y; tile[ks][n + 2] = v.z; tile[ks][n + 3] = v.w;
    }
    __syncthreads();
    ushort_t* BTl = BT + (size_t)l * 262144;
    #pragma unroll
    for (int p = 0; p < 2; p++) {
      int n  = p * 32 + (t >> 3);
      int kk = (t & 7) * 8;
      ushort_t hi[8], lo[8];
      #pragma unroll
      for (int j = 0; j < 8; j++) {
        float v = tile[kk + j][n];
        hi[j] = f2bf(v);
        lo[j] = f2bf(v - bf2f(hi[j]));
      }
      *(s8v*)&BTl[(size_t)(n0 + n) * 1024 + k0 + kk]       = *(const s8v*)hi;
      *(s8v*)&BTl[(size_t)(n0 + n) * 1024 + 512 + k0 + kk] = *(const s8v*)lo;
    }
  } else if (bid < 224) {
    int idx = (bid - 96) * 256 + t;   // n*128 + k
    int n = idx >> 7, k = idx & 127;
    int ks = k & 63;
    float v = 0.f;
    if (ks < DINF) v = Wi0[ks * 256 + n];
    else if (ks < 2 * DINF) v = Wo0[(ks - DINF) * 256 + n];
    ushort_t hi = f2bf(v);
    BT0[idx] = (k < 64) ? hi : f2bf(v - bf2f(hi));
  } else {
    // regloss partials over |Wo0| + |b_out0| + |Wo| + |b_out|
    int rb = bid - 224;               // 0..63
    int tid = rb * 256 + t;
    int stride = 64 * 256;
    float sum = 0.f;
    for (int i = tid; i < DINF * DD; i += stride)          sum += fabsf(Wo0[i]);
    for (int i = tid; i < DD; i += stride)                 sum += fabsf(b_out0[i]);
    for (int i = tid; i < (LL - 1) * DD * DD; i += stride) sum += fabsf(Wo[i]);
    for (int i = tid; i < (LL - 1) * DD; i += stride)      sum += fabsf(b_out[i]);
    __shared__ float red[8];
    float2 ss = block_reduce2(sum, 0.f, red);
    if (t == 0) partials[rb] = ss.x;
  }
}

// ---------------- bucket kernel with merged scan (block 0 scans; flag handoff) -------
// Round-8-verified pattern: block 0 publishes scan results via agent stores (L3),
// sets flag; other blocks spin relaxed (no cache maintenance) then bucket. cursor
// is consumed via atomicAdd (device-coherent RMW); dinv via agent loads.
__global__ __launch_bounds__(256) void bucket_kernel(const int* __restrict__ src,
                                                     const int* __restrict__ dst,
                                                     const int* __restrict__ mask,
                                                     const int* __restrict__ deg,
                                                     float* __restrict__ dinv,
                                                     int* __restrict__ row_ptr,
                                                     int* __restrict__ cursor,
                                                     int2* __restrict__ epk,
                                                     int* __restrict__ sflag) {
  int t = threadIdx.x;
  if (blockIdx.x == 0) {
    // full scan: 256 threads x 40 nodes, serial per-thread prefix + block scan
    __shared__ int ws[4];
    int base = t * 40;
    int dd[40];
    int sum = 0;
    #pragma unroll
    for (int i = 0; i < 10; i++) {
      int4 d4 = *(const int4*)&deg[base + i * 4];
      dd[i * 4] = d4.x; dd[i * 4 + 1] = d4.y; dd[i * 4 + 2] = d4.z; dd[i * 4 + 3] = d4.w;
      sum += d4.x + d4.y + d4.z + d4.w;
    }
    int lane = t & 63, wid = t >> 6;
    int v = sum;
    #pragma unroll
    for (int off = 1; off < 64; off <<= 1) {
      int u = __shfl_up(v, off);
      if (lane >= off) v += u;
    }
    if (lane == 63) ws[wid] = v;
    __syncthreads();
    int woff = 0;
    #pragma unroll
    for (int p = 0; p < 4; p++) woff += (p < wid) ? ws[p] : 0;
    int rp = woff + v - sum;
    #pragma unroll
    for (int i = 0; i < 10; i++) {
      int r[4]; unsigned dv[4];
      #pragma unroll
      for (int j = 0; j < 4; j++) {
        r[j] = rp;
        dv[j] = __float_as_uint(rsqrtf((float)max(dd[i * 4 + j], 1)));
        rp += dd[i * 4 + j];
      }
      ull r01 = (unsigned)r[0] | ((ull)(unsigned)r[1] << 32);
      ull r23 = (unsigned)r[2] | ((ull)(unsigned)r[3] << 32);
      ull d01 = dv[0] | ((ull)dv[1] << 32);
      ull d23 = dv[2] | ((ull)dv[3] << 32);
      ast64(&row_ptr[base + i * 4], r01); ast64(&row_ptr[base + i * 4 + 2], r23);
      ast64(&cursor[base + i * 4], r01);  ast64(&cursor[base + i * 4 + 2], r23);
      ast64(&dinv[base + i * 4], d01);    ast64(&dinv[base + i * 4 + 2], d23);
    }
    if (t == 0) ast32(&row_ptr[NN], EE);
    asm volatile("s_waitcnt vmcnt(0)" ::: "memory");
    __syncthreads();
    if (t == 0) ast32(sflag, 1);
  } else {
    if (t == 0) {
      int spins = 0;
      while (ald32(sflag) == 0) {
        __builtin_amdgcn_s_sleep(2);
        if (++spins > (1 << 22)) break;    // hang-proof escape
      }
    }
    __syncthreads();
  }
  int e = blockIdx.x * 256 + t;
  if (e >= EE) return;
  int sn = src[e], dn = dst[e];
  float fs = __int_as_float(ald32((const int*)&dinv[sn]));
  float fd = __int_as_float(ald32((const int*)&dinv[dn]));
  int p = atomicAdd(&cursor[dn], 1);
  epk[p] = make_int2(sn | (mask[e] ? (int)0x80000000 : 0), __float_as_int(fs * fd));
}

// ---------------- layer-0 aggregation: wave-per-node, 8 edges in flight ----------------
__global__ __launch_bounds__(256) void agg0_kernel(const float* __restrict__ x,
                                                   const int2* __restrict__ epk,
                                                   const int* __restrict__ row_ptr,
                                                   ushort_t* __restrict__ agg0b) {
  int n = blockIdx.x * 4 + (threadIdx.x >> 6);
  int lane = threadIdx.x & 63;
  int half = lane >> 5;
  int ch = lane & 31;
  int chc = (ch < DINF) ? ch : 0;      // clamped safe address; unused lanes never write
  int e0 = row_ptr[n], e1 = row_ptr[n + 1];
  float accI = 0.f, accO = 0.f;
  for (int c0 = e0; c0 < e1; c0 += 64) {
    int cnt = min(64, e1 - c0);
    int2 my = (lane < cnt) ? epk[c0 + lane] : make_int2(0, 0);
    int i = half;
    for (; i + 6 < cnt; i += 8) {       // this half handles i, i+2, i+4, i+6
      unsigned u[4]; float w[4], v[4];
      #pragma unroll
      for (int j = 0; j < 4; j++) {
        u[j] = (unsigned)__shfl(my.x, i + 2 * j);
        w[j] = __int_as_float(__shfl(my.y, i + 2 * j));
      }
      #pragma unroll
      for (int j = 0; j < 4; j++)
        v[j] = x[(size_t)(u[j] & 0x7fffffffu) * DINF + chc];
      #pragma unroll
      for (int j = 0; j < 4; j++) {
        float wI = (u[j] >> 31) ? w[j] : 0.f;  float wO = w[j] - wI;
        accI = fmaf(v[j], wI, accI); accO = fmaf(v[j], wO, accO);
      }
    }
    for (; i < cnt; i += 2) {
      unsigned u = (unsigned)__shfl(my.x, i);
      float w = __int_as_float(__shfl(my.y, i));
      float v = x[(size_t)(u & 0x7fffffffu) * DINF + chc];
      float wI = (u >> 31) ? w : 0.f;  float wO = w - wI;
      accI = fmaf(v, wI, accI); accO = fmaf(v, wO, accO);
    }
  }
  accI += __shfl_xor(accI, 32);
  accO += __shfl_xor(accO, 32);
  if (half == 0) {
    if (ch < DINF) {
      agg0b[(size_t)n * 64 + ch]        = f2bf(accI);
      agg0b[(size_t)n * 64 + DINF + ch] = f2bf(accO);
    } else {
      int k = 2 * DINF + (ch - DINF) * 2;
      agg0b[(size_t)n * 64 + k] = 0;
      agg0b[(size_t)n * 64 + k + 1] = 0;
    }
  }
}

// ---------------- layer 1-3 aggregation: wave-per-node, scalar metadata, 8 in flight --
__global__ __launch_bounds__(256) void agg_kernel(const ushort_t* __restrict__ h,
                                                  const int2* __restrict__ epk,
                                                  const int* __restrict__ row_ptr,
                                                  ushort_t* __restrict__ agg2b) {
  int n = blockIdx.x * 4 + (threadIdx.x >> 6);
  int lane = threadIdx.x & 63;
  int coff = lane * 4;
  int e0 = __builtin_amdgcn_readfirstlane(row_ptr[n]);
  int e1 = __builtin_amdgcn_readfirstlane(row_ptr[n + 1]);
  float aI0 = 0.f, aI1 = 0.f, aI2 = 0.f, aI3 = 0.f;
  float aO0 = 0.f, aO1 = 0.f, aO2 = 0.f, aO3 = 0.f;
  int i = e0;
  for (; i + 8 <= e1; i += 8) {
    int2 e[8];
    #pragma unroll
    for (int j = 0; j < 8; j++) e[j] = epk[i + j];
    ushort4 v[8];
    #pragma unroll
    for (int j = 0; j < 8; j++)
      v[j] = *(const ushort4*)&h[(size_t)(unsigned)(e[j].x & 0x7fffffff) * 256u + coff];
    #pragma unroll
    for (int j = 0; j < 8; j++) {
      float w = __int_as_float(e[j].y);
      float wI = (e[j].x < 0) ? w : 0.f;  float wO = w - wI;
      float f;
      f = bf2f(v[j].x); aI0 = fmaf(f, wI, aI0); aO0 = fmaf(f, wO, aO0);
      f = bf2f(v[j].y); aI1 = fmaf(f, wI, aI1); aO1 = fmaf(f, wO, aO1);
      f = bf2f(v[j].z); aI2 = fmaf(f, wI, aI2); aO2 = fmaf(f, wO, aO2);
      f = bf2f(v[j].w); aI3 = fmaf(f, wI, aI3); aO3 = fmaf(f, wO, aO3);
    }
  }
  for (; i < e1; i++) {
    int2 e = epk[i];
    ushort4 v = *(const ushort4*)&h[(size_t)(unsigned)(e.x & 0x7fffffff) * 256u + coff];
    float w = __int_as_float(e.y);
    float wI = (e.x < 0) ? w : 0.f;  float wO = w - wI;
    float f;
    f = bf2f(v.x); aI0 = fmaf(f, wI, aI0); aO0 = fmaf(f, wO, aO0);
    f = bf2f(v.y); aI1 = fmaf(f, wI, aI1); aO1 = fmaf(f, wO, aO1);
    f = bf2f(v.z); aI2 = fmaf(f, wI, aI2); aO2 = fmaf(f, wO, aO2);
    f = bf2f(v.w); aI3 = fmaf(f, wI, aI3); aO3 = fmaf(f, wO, aO3);
  }
  ushort_t* row = &agg2b[(size_t)n * 512];
  ushort4 pI, pO;
  pI.x = f2bf(aI0); pI.y = f2bf(aI1); pI.z = f2bf(aI2); pI.w = f2bf(aI3);
  pO.x = f2bf(aO0); pO.y = f2bf(aO1); pO.z = f2bf(aO2); pO.w = f2bf(aO3);
  *(ushort4*)&row[coff]       = pI;
  *(ushort4*)&row[256 + coff] = pO;
}

// ---------------- MFMA GEMM v2 (round-2 verified): gld16 staging, swizzled LDS -------
// 4 waves x (32 rows x 64 cols); 12 ds_read_b128 : 16 MFMA per K-step; 37 KB LDS.
template <int KB>
__global__ __launch_bounds__(256, 4) void gemm_mfma_ln(const ushort_t* __restrict__ A,
                                                       const ushort_t* __restrict__ BT,
                                                       const float* __restrict__ bi,
                                                       const float* __restrict__ bo,
                                                       const float* __restrict__ g,
                                                       const float* __restrict__ bb,
                                                       ushort_t* __restrict__ hout) {
  constexpr int AK = KB / 2;               // A row length (shorts)
  constexpr int ABR = AK * 2;              // A row bytes
  constexpr int BBR = KB * 2;              // BT row bytes
  __shared__ __align__(16) ushort_t As[32 * 64];
  __shared__ __align__(16) ushort_t Bs[256 * 64];
  __shared__ float redS[32][4];
  __shared__ float redQ[32][4];
  int t = threadIdx.x;
  int m0 = blockIdx.x * 32;
  int w = t >> 6;
  int lane = t & 63;
  int q = lane >> 4, n16 = lane & 15;
  int sx = (n16 & 7) << 3;                 // read-side swizzle (short units)
  f4v acc[2][4];
  #pragma unroll
  for (int rt = 0; rt < 2; rt++)
    #pragma unroll
    for (int ct = 0; ct < 4; ct++) acc[rt][ct] = (f4v){0.f, 0.f, 0.f, 0.f};

  int srow   = lane >> 3;
  int sobyte = (lane & 7) * 16;
  int arow   = w * 8 + srow;
  size_t a_base = (size_t)(m0 + arow) * ABR
                + (size_t)((unsigned)sobyte ^ ((unsigned)(arow & 7) << 4));
  char* as_dst = (char*)As + w * 1024;
  char* bs_dst = (char*)Bs + w * 8192;

  for (int k0 = 0; k0 < KB; k0 += 64) {
    __syncthreads();                       // previous tile fully consumed
    gld16((const char*)A + a_base + (size_t)((k0 & (AK - 1)) * 2), as_dst);
    #pragma unroll
    for (int j = 0; j < 8; j++) {
      int brow = w * 64 + j * 8 + srow;
      gld16((const char*)BT + (size_t)brow * BBR + (size_t)(k0 * 2)
                + (size_t)((unsigned)sobyte ^ ((unsigned)(brow & 7) << 4)),
            bs_dst + j * 1024);
    }
    asm volatile("s_waitcnt vmcnt(0)" ::: "memory");
    __syncthreads();                       // tile ready
    #pragma unroll
    for (int kk = 0; kk < 2; kk++) {
      int ko = (kk * 32 + q * 8) ^ sx;
      s8v af0 = *(const s8v*)&As[n16 * 64 + ko];
      s8v af1 = *(const s8v*)&As[(16 + n16) * 64 + ko];
      #pragma unroll
      for (int ct = 0; ct < 4; ct++) {
        s8v bf = *(const s8v*)&Bs[(w * 64 + ct * 16 + n16) * 64 + ko];
        acc[0][ct] = __builtin_amdgcn_mfma_f32_16x16x32_bf16(af0, bf, acc[0][ct], 0, 0, 0);
        acc[1][ct] = __builtin_amdgcn_mfma_f32_16x16x32_bf16(af1, bf, acc[1][ct], 0, 0, 0);
      }
    }
  }

  // epilogue: bias, row-LN across the 4 col-quarter waves, ReLU, bf16 store
  float biv[4], gv[4], bbv[4];
  #pragma unroll
  for (int ct = 0; ct < 4; ct++) {
    int c = w * 64 + ct * 16 + n16;
    biv[ct] = bi[c] + bo[c];
    gv[ct]  = g[c];
    bbv[ct] = bb[c];
  }
  #pragma unroll
  for (int rt = 0; rt < 2; rt++)
    #pragma unroll
    for (int rg = 0; rg < 4; rg++) {
      float s = 0.f, ss = 0.f;
      #pragma unroll
      for (int ct = 0; ct < 4; ct++) {
        float v = acc[rt][ct][rg] + biv[ct];
        s += v; ss += v * v;
      }
      #pragma unroll
      for (int off = 1; off < 16; off <<= 1) {
        s  += __shfl_xor(s, off);
        ss += __shfl_xor(ss, off);
      }
      if (n16 == 0) {
        int row = rt * 16 + q * 4 + rg;
        redS[row][w] = s;
        redQ[row][w] = ss;
      }
    }
  __syncthreads();
  #pragma unroll
  for (int rt = 0; rt < 2; rt++)
    #pragma unroll
    for (int rg = 0; rg < 4; rg++) {
      int row = rt * 16 + q * 4 + rg;
      float mean = (redS[row][0] + redS[row][1] + redS[row][2] + redS[row][3]) * (1.f / 256.f);
      float var  = (redQ[row][0] + redQ[row][1] + redQ[row][2] + redQ[row][3]) * (1.f / 256.f)
                   - mean * mean;
      float rs = rsqrtf(fmaxf(var, 0.f) + LNEPS);
      #pragma unroll
      for (int ct = 0; ct < 4; ct++) {
        float v = acc[rt][ct][rg] + biv[ct];
        float o = fmaxf((v - mean) * rs * gv[ct] + bbv[ct], 0.f);
        hout[(size_t)(m0 + row) * 256 + w * 64 + ct * 16 + n16] = f2bf(o);
      }
    }
}

// ---------------- fragment pooling + LN + mask; extra block finalizes regloss --------
__global__ __launch_bounds__(256) void frag_pool_kernel(const ushort_t* __restrict__ h,
                                                        const int* __restrict__ fid,
                                                        const float* __restrict__ g,
                                                        const float* __restrict__ bb,
                                                        const float* __restrict__ partials,
                                                        float* __restrict__ out_emb,
                                                        float* __restrict__ out_mask,
                                                        float* __restrict__ out_reg) {
  int d = threadIdx.x;
  if (blockIdx.x == BGR * KK) {       // regloss final: sum 64 partials
    if (d < 64) {
      float sv = partials[d];
      #pragma unroll
      for (int off = 32; off > 0; off >>= 1) sv += __shfl_down(sv, off);
      if (d == 0) out_reg[0] = sv;
    }
    return;
  }
  int b = blockIdx.x >> 4;
  int k = blockIdx.x & 15;
  __shared__ int list[NPG];
  __shared__ int cnt;
  __shared__ float red[8];
  if (d == 0) cnt = 0;
  __syncthreads();
  int base = b * NPG;
  if (d < NPG) {
    if (fid[base + d] == k) { int p = atomicAdd(&cnt, 1); list[p] = d; }
  }
  __syncthreads();
  int c = cnt;
  float acc = 0.f;
  int i = 0;
  for (; i + 4 <= c; i += 4) {
    int l0 = list[i], l1 = list[i + 1], l2 = list[i + 2], l3 = list[i + 3];
    float a0 = bf2f(h[(size_t)(base + l0) * 256 + d]);
    float a1 = bf2f(h[(size_t)(base + l1) * 256 + d]);
    float a2 = bf2f(h[(size_t)(base + l2) * 256 + d]);
    float a3 = bf2f(h[(size_t)(base + l3) * 256 + d]);
    acc += (a0 + a1) + (a2 + a3);
  }
  for (; i < c; i++) {
    acc += bf2f(h[(size_t)(base + list[i]) * 256 + d]);
  }
  float2 ss = block_reduce2(acc, acc * acc, red);
  float mean = ss.x * (1.f / 256.f);
  float var  = ss.y * (1.f / 256.f) - mean * mean;
  float o = (acc - mean) * rsqrtf(fmaxf(var, 0.f) + LNEPS) * g[d] + bb[d];
  out_emb[((size_t)b * KK + k) * 256 + d] = o;
  if (d == 0) out_mask[b * KK + k] = (c > 0) ? 1.f : 0.f;
}

// ---------------- launch ----------------
static inline size_t align256(size_t x) { return (x + 255) & ~(size_t)255; }

extern "C" void kernel_launch(void* const* d_in, const int* in_sizes, int n_in,
                              void* d_out, int out_size, void* d_ws, size_t ws_size,
                              hipStream_t stream) {
  const float* x      = (const float*)d_in[0];
  const int*   ei     = (const int*)d_in[1];
  const int*   mask   = (const int*)d_in[2];
  const float* s      = (const float*)d_in[3];
  const float* W_in0  = (const float*)d_in[5];
  const float* W_out0 = (const float*)d_in[6];
  const float* b_in0  = (const float*)d_in[7];
  const float* b_out0 = (const float*)d_in[8];
  const float* W_in   = (const float*)d_in[9];
  const float* W_out  = (const float*)d_in[10];
  const float* b_in   = (const float*)d_in[11];
  const float* b_out  = (const float*)d_in[12];
  const float* ln_g   = (const float*)d_in[13];
  const float* ln_b   = (const float*)d_in[14];
  const float* fbn_g  = (const float*)d_in[15];
  const float* fbn_b  = (const float*)d_in[16];

  const int* src = ei;
  const int* dst = ei + EE;

  char* w = (char*)d_ws;
  int*      deg     = (int*)w;      w += align256((size_t)NN * 4);
  int*      bar     = (int*)w;      w += 256;                       // scan->bucket flag
  int*      row_ptr = (int*)w;      w += align256((size_t)(NN + 1) * 4);
  int*      cursor  = (int*)w;      w += align256((size_t)NN * 4);
  float*    dinv    = (float*)w;    w += align256((size_t)NN * 4);
  int*      fid     = (int*)w;      w += align256((size_t)NN * 4);
  float*    rlpart  = (float*)w;    w += align256((size_t)64 * 4);
  int2*     epk     = (int2*)w;     w += align256((size_t)EE * 8);
  ushort_t* BT0     = (ushort_t*)w; w += align256((size_t)256 * 128 * 2);
  ushort_t* BTw     = (ushort_t*)w; w += align256((size_t)3 * 256 * 1024 * 2);
  ushort_t* agg0b   = (ushort_t*)w; w += align256((size_t)NN * 64 * 2);
  ushort_t* agg2b   = (ushort_t*)w; w += align256((size_t)NN * 512 * 2);
  ushort_t* hbuf    = (ushort_t*)w; w += align256((size_t)NN * 256 * 2);

  float* out_emb  = (float*)d_out;
  float* out_mask = out_emb + (size_t)BGR * KK * DD;
  float* out_reg  = out_emb + (size_t)out_size - 1;

  // zero deg + flag (contiguous)
  hipMemsetAsync(deg, 0, (size_t)NN * 4 + 256, stream);

  setup_kernel<<<1250 + 288, 256, 0, stream>>>(dst, s, W_in, W_out, W_in0, W_out0,
                                               b_out0, b_out, deg, fid, BTw, BT0, rlpart);
  bucket_kernel<<<(EE + 255) / 256, 256, 0, stream>>>(src, dst, mask, deg, dinv,
                                                      row_ptr, cursor, epk, bar);

  // layer 0: aggregate x, then MFMA transform + LN + ReLU
  agg0_kernel<<<NN / 4, 256, 0, stream>>>(x, epk, row_ptr, agg0b);
  gemm_mfma_ln<128><<<NN / 32, 256, 0, stream>>>(agg0b, BT0, b_in0, b_out0, ln_g, ln_b, hbuf);
  // layers 1..3
  for (int l = 0; l < LL - 1; l++) {
    agg_kernel<<<NN / 4, 256, 0, stream>>>(hbuf, epk, row_ptr, agg2b);
    gemm_mfma_ln<1024><<<NN / 32, 256, 0, stream>>>(agg2b, BTw + (size_t)l * 262144,
                                                    b_in + l * 256, b_out + l * 256,
                                                    ln_g + (l + 1) * 256, ln_b + (l + 1) * 256,
                                                    hbuf);
  }

  frag_pool_kernel<<<BGR * KK + 1, 256, 0, stream>>>(hbuf, fid, fbn_g, fbn_b, rlpart,
                                                     out_emb, out_mask, out_reg);
}

// Round 10
// 297.251 us; speedup vs baseline: 10.0666x; 1.0005x over previous
//
#include <hip/hip_runtime.h>

#define NN   10240
#define EE   320000
#define BGR  64
#define NPG  160
#define KK   16
#define DINF 25
#define DD   256
#define LL   4
#define LNEPS 1e-5f

typedef unsigned short ushort_t;
typedef unsigned long long ull;
typedef __attribute__((ext_vector_type(8))) short s8v;
typedef __attribute__((ext_vector_type(4))) float f4v;

__device__ __forceinline__ float bf2f(ushort_t u) {
  union { unsigned u; float f; } a; a.u = ((unsigned)u) << 16; return a.f;
}
__device__ __forceinline__ ushort_t f2bf(float f) {
  union { float f; unsigned u; } a; a.f = f;
  unsigned r = (a.u + 0x7fffu + ((a.u >> 16) & 1u)) >> 16;   // RNE
  return (ushort_t)r;
}

// agent-scope relaxed atomics (L3 coherence point) — ONLY for the scan->bucket
// CONTROL handoff (flag + block-0's publication of scan results). Round-8/9 lesson:
// bulk/consumer DATA reads must stay on the cached path; consumers here read dinv
// with normal loads — safe because no dinv line is touched before the flag, and all
// L2s are clean at dispatch start (CP boundary flush), so fills pull fresh L3 data.
__device__ __forceinline__ void ast64(void* p, ull v) {
  __hip_atomic_store((ull*)p, v, __ATOMIC_RELAXED, __HIP_MEMORY_SCOPE_AGENT);
}
__device__ __forceinline__ void ast32(int* p, int v) {
  __hip_atomic_store(p, v, __ATOMIC_RELAXED, __HIP_MEMORY_SCOPE_AGENT);
}
__device__ __forceinline__ int ald32(const int* p) {
  return __hip_atomic_load(p, __ATOMIC_RELAXED, __HIP_MEMORY_SCOPE_AGENT);
}

// async global->LDS DMA, 16B per lane, dest = wave-uniform base + lane*16
__device__ __forceinline__ void gld16(const void* g, void* l) {
  __builtin_amdgcn_global_load_lds(
      (const __attribute__((address_space(1))) unsigned int*)g,
      (__attribute__((address_space(3))) unsigned int*)l, 16, 0, 0);
}

// ---------------- block reduce (256 threads = 4 waves) ----------------
__device__ __forceinline__ float2 block_reduce2(float a, float b, float* red) {
  __syncthreads();
  #pragma unroll
  for (int off = 32; off > 0; off >>= 1) {
    a += __shfl_down(a, off);
    b += __shfl_down(b, off);
  }
  int lane = threadIdx.x & 63;
  int wid  = threadIdx.x >> 6;
  if (lane == 0) { red[wid * 2] = a; red[wid * 2 + 1] = b; }
  __syncthreads();
  float sa = red[0] + red[2] + red[4] + red[6];
  float sb = red[1] + red[3] + red[5] + red[7];
  return make_float2(sa, sb);
}

// ---------------- setup (merged): degfid + weight prep + regloss partials ----------------
__global__ __launch_bounds__(256) void setup_kernel(const int* __restrict__ dst,
                                                    const float* __restrict__ s,
                                                    const float* __restrict__ Wi,
                                                    const float* __restrict__ Wo,
                                                    const float* __restrict__ Wi0,
                                                    const float* __restrict__ Wo0,
                                                    const float* __restrict__ b_out0,
                                                    const float* __restrict__ b_out,
                                                    int* __restrict__ deg,
                                                    int* __restrict__ fid,
                                                    ushort_t* __restrict__ BT,
                                                    ushort_t* __restrict__ BT0,
                                                    float* __restrict__ partials) {
  int bid0 = blockIdx.x;
  int t = threadIdx.x;
  if (bid0 < 1250) {
    int e = bid0 * 256 + t;
    if (e < EE) atomicAdd(&deg[dst[e]], 1);
    if (e < NN) {
      int k = 0;
      #pragma unroll
      for (int j = 0; j < KK; j++) if (s[e * KK + j] > 0.5f) k = j;
      fid[e] = k;
    }
    return;
  }
  int bid = bid0 - 1250;
  if (bid < 96) {
    int l = bid >> 5, rem = bid & 31;
    int kb = rem >> 2, nb = rem & 3;
    int k0 = kb * 64, n0 = nb * 64;
    __shared__ float tile[64][65];
    const float* Wl = (k0 < 256) ? (Wi + (size_t)l * 65536 + (size_t)k0 * 256)
                                 : (Wo + (size_t)l * 65536 + (size_t)(k0 - 256) * 256);
    #pragma unroll
    for (int p = 0; p < 4; p++) {
      int ks = p * 16 + (t >> 4);
      int n  = (t & 15) * 4;
      float4 v = *(const float4*)&Wl[(size_t)ks * 256 + n0 + n];
      tile[ks][n] = v.x; tile[ks][n + 1] = v.y; tile[ks][n + 2] = v.z; tile[ks][n + 3] = v.w;
    }
    __syncthreads();
    ushort_t* BTl = BT + (size_t)l * 262144;
    #pragma unroll
    for (int p = 0; p < 2; p++) {
      int n  = p * 32 + (t >> 3);
      int kk = (t & 7) * 8;
      ushort_t hi[8], lo[8];
      #pragma unroll
      for (int j = 0; j < 8; j++) {
        float v = tile[kk + j][n];
        hi[j] = f2bf(v);
        lo[j] = f2bf(v - bf2f(hi[j]));
      }
      *(s8v*)&BTl[(size_t)(n0 + n) * 1024 + k0 + kk]       = *(const s8v*)hi;
      *(s8v*)&BTl[(size_t)(n0 + n) * 1024 + 512 + k0 + kk] = *(const s8v*)lo;
    }
  } else if (bid < 224) {
    int idx = (bid - 96) * 256 + t;   // n*128 + k
    int n = idx >> 7, k = idx & 127;
    int ks = k & 63;
    float v = 0.f;
    if (ks < DINF) v = Wi0[ks * 256 + n];
    else if (ks < 2 * DINF) v = Wo0[(ks - DINF) * 256 + n];
    ushort_t hi = f2bf(v);
    BT0[idx] = (k < 64) ? hi : f2bf(v - bf2f(hi));
  } else {
    // regloss partials over |Wo0| + |b_out0| + |Wo| + |b_out|
    int rb = bid - 224;               // 0..63
    int tid = rb * 256 + t;
    int stride = 64 * 256;
    float sum = 0.f;
    for (int i = tid; i < DINF * DD; i += stride)          sum += fabsf(Wo0[i]);
    for (int i = tid; i < DD; i += stride)                 sum += fabsf(b_out0[i]);
    for (int i = tid; i < (LL - 1) * DD * DD; i += stride) sum += fabsf(Wo[i]);
    for (int i = tid; i < (LL - 1) * DD; i += stride)      sum += fabsf(b_out[i]);
    __shared__ float red[8];
    float2 ss = block_reduce2(sum, 0.f, red);
    if (t == 0) partials[rb] = ss.x;
  }
}

// ---------------- bucket kernel with merged scan (block 0 scans; flag handoff) -------
// block 0 publishes scan output via agent stores (L3) and sets flag after vmcnt(0);
// other blocks hoist their edge loads (scan-independent, latency hides under spin),
// spin relaxed (no cache maintenance — round-6/7 lesson), then read dinv via NORMAL
// cached loads (round-9 fix: the agent-load path was uncached, +20us).
__global__ __launch_bounds__(256) void bucket_kernel(const int* __restrict__ src,
                                                     const int* __restrict__ dst,
                                                     const int* __restrict__ mask,
                                                     const int* __restrict__ deg,
                                                     float* __restrict__ dinv,
                                                     int* __restrict__ row_ptr,
                                                     int* __restrict__ cursor,
                                                     int2* __restrict__ epk,
                                                     int* __restrict__ sflag) {
  int t = threadIdx.x;
  int e = blockIdx.x * 256 + t;
  // hoisted edge loads — independent of the scan, overlap the wait
  int sn = 0, dn = 0, mk = 0;
  if (e < EE) { sn = src[e]; dn = dst[e]; mk = mask[e]; }
  if (blockIdx.x == 0) {
    // full scan: 256 threads x 40 nodes, serial per-thread prefix + block scan
    __shared__ int ws[4];
    int base = t * 40;
    int dd[40];
    int sum = 0;
    #pragma unroll
    for (int i = 0; i < 10; i++) {
      int4 d4 = *(const int4*)&deg[base + i * 4];
      dd[i * 4] = d4.x; dd[i * 4 + 1] = d4.y; dd[i * 4 + 2] = d4.z; dd[i * 4 + 3] = d4.w;
      sum += d4.x + d4.y + d4.z + d4.w;
    }
    int lane = t & 63, wid = t >> 6;
    int v = sum;
    #pragma unroll
    for (int off = 1; off < 64; off <<= 1) {
      int u = __shfl_up(v, off);
      if (lane >= off) v += u;
    }
    if (lane == 63) ws[wid] = v;
    __syncthreads();
    int woff = 0;
    #pragma unroll
    for (int p = 0; p < 4; p++) woff += (p < wid) ? ws[p] : 0;
    int rp = woff + v - sum;
    #pragma unroll
    for (int i = 0; i < 10; i++) {
      int r[4]; unsigned dv[4];
      #pragma unroll
      for (int j = 0; j < 4; j++) {
        r[j] = rp;
        dv[j] = __float_as_uint(rsqrtf((float)max(dd[i * 4 + j], 1)));
        rp += dd[i * 4 + j];
      }
      ull r01 = (unsigned)r[0] | ((ull)(unsigned)r[1] << 32);
      ull r23 = (unsigned)r[2] | ((ull)(unsigned)r[3] << 32);
      ull d01 = dv[0] | ((ull)dv[1] << 32);
      ull d23 = dv[2] | ((ull)dv[3] << 32);
      ast64(&row_ptr[base + i * 4], r01); ast64(&row_ptr[base + i * 4 + 2], r23);
      ast64(&cursor[base + i * 4], r01);  ast64(&cursor[base + i * 4 + 2], r23);
      ast64(&dinv[base + i * 4], d01);    ast64(&dinv[base + i * 4 + 2], d23);
    }
    if (t == 0) ast32(&row_ptr[NN], EE);
    asm volatile("s_waitcnt vmcnt(0)" ::: "memory");   // scan data at L3
    __syncthreads();
    if (t == 0) ast32(sflag, 1);
  } else {
    if (t == 0) {
      int spins = 0;
      while (ald32(sflag) == 0) {
        __builtin_amdgcn_s_sleep(2);
        if (++spins > (1 << 22)) break;    // hang-proof escape
      }
    }
    __syncthreads();
  }
  asm volatile("" ::: "memory");           // no hoisting of dinv loads above the spin
  if (e >= EE) return;
  float fs = dinv[sn];                     // normal cached loads (L1/L2, ~60x reuse)
  float fd = dinv[dn];
  int p = atomicAdd(&cursor[dn], 1);
  epk[p] = make_int2(sn | (mk ? (int)0x80000000 : 0), __float_as_int(fs * fd));
}

// ---------------- layer-0 aggregation: wave-per-node, 8 edges in flight ----------------
__global__ __launch_bounds__(256) void agg0_kernel(const float* __restrict__ x,
                                                   const int2* __restrict__ epk,
                                                   const int* __restrict__ row_ptr,
                                                   ushort_t* __restrict__ agg0b) {
  int n = blockIdx.x * 4 + (threadIdx.x >> 6);
  int lane = threadIdx.x & 63;
  int half = lane >> 5;
  int ch = lane & 31;
  int chc = (ch < DINF) ? ch : 0;      // clamped safe address; unused lanes never write
  int e0 = row_ptr[n], e1 = row_ptr[n + 1];
  float accI = 0.f, accO = 0.f;
  for (int c0 = e0; c0 < e1; c0 += 64) {
    int cnt = min(64, e1 - c0);
    int2 my = (lane < cnt) ? epk[c0 + lane] : make_int2(0, 0);
    int i = half;
    for (; i + 6 < cnt; i += 8) {       // this half handles i, i+2, i+4, i+6
      unsigned u[4]; float w[4], v[4];
      #pragma unroll
      for (int j = 0; j < 4; j++) {
        u[j] = (unsigned)__shfl(my.x, i + 2 * j);
        w[j] = __int_as_float(__shfl(my.y, i + 2 * j));
      }
      #pragma unroll
      for (int j = 0; j < 4; j++)
        v[j] = x[(size_t)(u[j] & 0x7fffffffu) * DINF + chc];
      #pragma unroll
      for (int j = 0; j < 4; j++) {
        float wI = (u[j] >> 31) ? w[j] : 0.f;  float wO = w[j] - wI;
        accI = fmaf(v[j], wI, accI); accO = fmaf(v[j], wO, accO);
      }
    }
    for (; i < cnt; i += 2) {
      unsigned u = (unsigned)__shfl(my.x, i);
      float w = __int_as_float(__shfl(my.y, i));
      float v = x[(size_t)(u & 0x7fffffffu) * DINF + chc];
      float wI = (u >> 31) ? w : 0.f;  float wO = w - wI;
      accI = fmaf(v, wI, accI); accO = fmaf(v, wO, accO);
    }
  }
  accI += __shfl_xor(accI, 32);
  accO += __shfl_xor(accO, 32);
  if (half == 0) {
    if (ch < DINF) {
      agg0b[(size_t)n * 64 + ch]        = f2bf(accI);
      agg0b[(size_t)n * 64 + DINF + ch] = f2bf(accO);
    } else {
      int k = 2 * DINF + (ch - DINF) * 2;
      agg0b[(size_t)n * 64 + k] = 0;
      agg0b[(size_t)n * 64 + k + 1] = 0;
    }
  }
}

// ---------------- layer 1-3 aggregation: wave-per-node, scalar metadata, 8 in flight --
__global__ __launch_bounds__(256) void agg_kernel(const ushort_t* __restrict__ h,
                                                  const int2* __restrict__ epk,
                                                  const int* __restrict__ row_ptr,
                                                  ushort_t* __restrict__ agg2b) {
  int n = blockIdx.x * 4 + (threadIdx.x >> 6);
  int lane = threadIdx.x & 63;
  int coff = lane * 4;
  int e0 = __builtin_amdgcn_readfirstlane(row_ptr[n]);
  int e1 = __builtin_amdgcn_readfirstlane(row_ptr[n + 1]);
  float aI0 = 0.f, aI1 = 0.f, aI2 = 0.f, aI3 = 0.f;
  float aO0 = 0.f, aO1 = 0.f, aO2 = 0.f, aO3 = 0.f;
  int i = e0;
  for (; i + 8 <= e1; i += 8) {
    int2 e[8];
    #pragma unroll
    for (int j = 0; j < 8; j++) e[j] = epk[i + j];
    ushort4 v[8];
    #pragma unroll
    for (int j = 0; j < 8; j++)
      v[j] = *(const ushort4*)&h[(size_t)(unsigned)(e[j].x & 0x7fffffff) * 256u + coff];
    #pragma unroll
    for (int j = 0; j < 8; j++) {
      float w = __int_as_float(e[j].y);
      float wI = (e[j].x < 0) ? w : 0.f;  float wO = w - wI;
      float f;
      f = bf2f(v[j].x); aI0 = fmaf(f, wI, aI0); aO0 = fmaf(f, wO, aO0);
      f = bf2f(v[j].y); aI1 = fmaf(f, wI, aI1); aO1 = fmaf(f, wO, aO1);
      f = bf2f(v[j].z); aI2 = fmaf(f, wI, aI2); aO2 = fmaf(f, wO, aO2);
      f = bf2f(v[j].w); aI3 = fmaf(f, wI, aI3); aO3 = fmaf(f, wO, aO3);
    }
  }
  for (; i < e1; i++) {
    int2 e = epk[i];
    ushort4 v = *(const ushort4*)&h[(size_t)(unsigned)(e.x & 0x7fffffff) * 256u + coff];
    float w = __int_as_float(e.y);
    float wI = (e.x < 0) ? w : 0.f;  float wO = w - wI;
    float f;
    f = bf2f(v.x); aI0 = fmaf(f, wI, aI0); aO0 = fmaf(f, wO, aO0);
    f = bf2f(v.y); aI1 = fmaf(f, wI, aI1); aO1 = fmaf(f, wO, aO1);
    f = bf2f(v.z); aI2 = fmaf(f, wI, aI2); aO2 = fmaf(f, wO, aO2);
    f = bf2f(v.w); aI3 = fmaf(f, wI, aI3); aO3 = fmaf(f, wO, aO3);
  }
  ushort_t* row = &agg2b[(size_t)n * 512];
  ushort4 pI, pO;
  pI.x = f2bf(aI0); pI.y = f2bf(aI1); pI.z = f2bf(aI2); pI.w = f2bf(aI3);
  pO.x = f2bf(aO0); pO.y = f2bf(aO1); pO.z = f2bf(aO2); pO.w = f2bf(aO3);
  *(ushort4*)&row[coff]       = pI;
  *(ushort4*)&row[256 + coff] = pO;
}

// ---------------- MFMA GEMM v2 (round-2 verified): gld16 staging, swizzled LDS -------
// 4 waves x (32 rows x 64 cols); 12 ds_read_b128 : 16 MFMA per K-step; 37 KB LDS.
template <int KB>
__global__ __launch_bounds__(256, 4) void gemm_mfma_ln(const ushort_t* __restrict__ A,
                                                       const ushort_t* __restrict__ BT,
                                                       const float* __restrict__ bi,
                                                       const float* __restrict__ bo,
                                                       const float* __restrict__ g,
                                                       const float* __restrict__ bb,
                                                       ushort_t* __restrict__ hout) {
  constexpr int AK = KB / 2;               // A row length (shorts)
  constexpr int ABR = AK * 2;              // A row bytes
  constexpr int BBR = KB * 2;              // BT row bytes
  __shared__ __align__(16) ushort_t As[32 * 64];
  __shared__ __align__(16) ushort_t Bs[256 * 64];
  __shared__ float redS[32][4];
  __shared__ float redQ[32][4];
  int t = threadIdx.x;
  int m0 = blockIdx.x * 32;
  int w = t >> 6;
  int lane = t & 63;
  int q = lane >> 4, n16 = lane & 15;
  int sx = (n16 & 7) << 3;                 // read-side swizzle (short units)
  f4v acc[2][4];
  #pragma unroll
  for (int rt = 0; rt < 2; rt++)
    #pragma unroll
    for (int ct = 0; ct < 4; ct++) acc[rt][ct] = (f4v){0.f, 0.f, 0.f, 0.f};

  int srow   = lane >> 3;
  int sobyte = (lane & 7) * 16;
  int arow   = w * 8 + srow;
  size_t a_base = (size_t)(m0 + arow) * ABR
                + (size_t)((unsigned)sobyte ^ ((unsigned)(arow & 7) << 4));
  char* as_dst = (char*)As + w * 1024;
  char* bs_dst = (char*)Bs + w * 8192;

  for (int k0 = 0; k0 < KB; k0 += 64) {
    __syncthreads();                       // previous tile fully consumed
    gld16((const char*)A + a_base + (size_t)((k0 & (AK - 1)) * 2), as_dst);
    #pragma unroll
    for (int j = 0; j < 8; j++) {
      int brow = w * 64 + j * 8 + srow;
      gld16((const char*)BT + (size_t)brow * BBR + (size_t)(k0 * 2)
                + (size_t)((unsigned)sobyte ^ ((unsigned)(brow & 7) << 4)),
            bs_dst + j * 1024);
    }
    asm volatile("s_waitcnt vmcnt(0)" ::: "memory");
    __syncthreads();                       // tile ready
    #pragma unroll
    for (int kk = 0; kk < 2; kk++) {
      int ko = (kk * 32 + q * 8) ^ sx;
      s8v af0 = *(const s8v*)&As[n16 * 64 + ko];
      s8v af1 = *(const s8v*)&As[(16 + n16) * 64 + ko];
      #pragma unroll
      for (int ct = 0; ct < 4; ct++) {
        s8v bf = *(const s8v*)&Bs[(w * 64 + ct * 16 + n16) * 64 + ko];
        acc[0][ct] = __builtin_amdgcn_mfma_f32_16x16x32_bf16(af0, bf, acc[0][ct], 0, 0, 0);
        acc[1][ct] = __builtin_amdgcn_mfma_f32_16x16x32_bf16(af1, bf, acc[1][ct], 0, 0, 0);
      }
    }
  }

  // epilogue: bias, row-LN across the 4 col-quarter waves, ReLU, bf16 store
  float biv[4], gv[4], bbv[4];
  #pragma unroll
  for (int ct = 0; ct < 4; ct++) {
    int c = w * 64 + ct * 16 + n16;
    biv[ct] = bi[c] + bo[c];
    gv[ct]  = g[c];
    bbv[ct] = bb[c];
  }
  #pragma unroll
  for (int rt = 0; rt < 2; rt++)
    #pragma unroll
    for (int rg = 0; rg < 4; rg++) {
      float s = 0.f, ss = 0.f;
      #pragma unroll
      for (int ct = 0; ct < 4; ct++) {
        float v = acc[rt][ct][rg] + biv[ct];
        s += v; ss += v * v;
      }
      #pragma unroll
      for (int off = 1; off < 16; off <<= 1) {
        s  += __shfl_xor(s, off);
        ss += __shfl_xor(ss, off);
      }
      if (n16 == 0) {
        int row = rt * 16 + q * 4 + rg;
        redS[row][w] = s;
        redQ[row][w] = ss;
      }
    }
  __syncthreads();
  #pragma unroll
  for (int rt = 0; rt < 2; rt++)
    #pragma unroll
    for (int rg = 0; rg < 4; rg++) {
      int row = rt * 16 + q * 4 + rg;
      float mean = (redS[row][0] + redS[row][1] + redS[row][2] + redS[row][3]) * (1.f / 256.f);
      float var  = (redQ[row][0] + redQ[row][1] + redQ[row][2] + redQ[row][3]) * (1.f / 256.f)
                   - mean * mean;
      float rs = rsqrtf(fmaxf(var, 0.f) + LNEPS);
      #pragma unroll
      for (int ct = 0; ct < 4; ct++) {
        float v = acc[rt][ct][rg] + biv[ct];
        float o = fmaxf((v - mean) * rs * gv[ct] + bbv[ct], 0.f);
        hout[(size_t)(m0 + row) * 256 + w * 64 + ct * 16 + n16] = f2bf(o);
      }
    }
}

// ---------------- fragment pooling + LN + mask; extra block finalizes regloss --------
__global__ __launch_bounds__(256) void frag_pool_kernel(const ushort_t* __restrict__ h,
                                                        const int* __restrict__ fid,
                                                        const float* __restrict__ g,
                                                        const float* __restrict__ bb,
                                                        const float* __restrict__ partials,
                                                        float* __restrict__ out_emb,
                                                        float* __restrict__ out_mask,
                                                        float* __restrict__ out_reg) {
  int d = threadIdx.x;
  if (blockIdx.x == BGR * KK) {       // regloss final: sum 64 partials
    if (d < 64) {
      float sv = partials[d];
      #pragma unroll
      for (int off = 32; off > 0; off >>= 1) sv += __shfl_down(sv, off);
      if (d == 0) out_reg[0] = sv;
    }
    return;
  }
  int b = blockIdx.x >> 4;
  int k = blockIdx.x & 15;
  __shared__ int list[NPG];
  __shared__ int cnt;
  __shared__ float red[8];
  if (d == 0) cnt = 0;
  __syncthreads();
  int base = b * NPG;
  if (d < NPG) {
    if (fid[base + d] == k) { int p = atomicAdd(&cnt, 1); list[p] = d; }
  }
  __syncthreads();
  int c = cnt;
  float acc = 0.f;
  int i = 0;
  for (; i + 4 <= c; i += 4) {
    int l0 = list[i], l1 = list[i + 1], l2 = list[i + 2], l3 = list[i + 3];
    float a0 = bf2f(h[(size_t)(base + l0) * 256 + d]);
    float a1 = bf2f(h[(size_t)(base + l1) * 256 + d]);
    float a2 = bf2f(h[(size_t)(base + l2) * 256 + d]);
    float a3 = bf2f(h[(size_t)(base + l3) * 256 + d]);
    acc += (a0 + a1) + (a2 + a3);
  }
  for (; i < c; i++) {
    acc += bf2f(h[(size_t)(base + list[i]) * 256 + d]);
  }
  float2 ss = block_reduce2(acc, acc * acc, red);
  float mean = ss.x * (1.f / 256.f);
  float var  = ss.y * (1.f / 256.f) - mean * mean;
  float o = (acc - mean) * rsqrtf(fmaxf(var, 0.f) + LNEPS) * g[d] + bb[d];
  out_emb[((size_t)b * KK + k) * 256 + d] = o;
  if (d == 0) out_mask[b * KK + k] = (c > 0) ? 1.f : 0.f;
}

// ---------------- launch ----------------
static inline size_t align256(size_t x) { return (x + 255) & ~(size_t)255; }

extern "C" void kernel_launch(void* const* d_in, const int* in_sizes, int n_in,
                              void* d_out, int out_size, void* d_ws, size_t ws_size,
                              hipStream_t stream) {
  const float* x      = (const float*)d_in[0];
  const int*   ei     = (const int*)d_in[1];
  const int*   mask   = (const int*)d_in[2];
  const float* s      = (const float*)d_in[3];
  const float* W_in0  = (const float*)d_in[5];
  const float* W_out0 = (const float*)d_in[6];
  const float* b_in0  = (const float*)d_in[7];
  const float* b_out0 = (const float*)d_in[8];
  const float* W_in   = (const float*)d_in[9];
  const float* W_out  = (const float*)d_in[10];
  const float* b_in   = (const float*)d_in[11];
  const float* b_out  = (const float*)d_in[12];
  const float* ln_g   = (const float*)d_in[13];
  const float* ln_b   = (const float*)d_in[14];
  const float* fbn_g  = (const float*)d_in[15];
  const float* fbn_b  = (const float*)d_in[16];

  const int* src = ei;
  const int* dst = ei + EE;

  char* w = (char*)d_ws;
  int*      deg     = (int*)w;      w += align256((size_t)NN * 4);
  int*      bar     = (int*)w;      w += 256;                       // scan->bucket flag
  int*      row_ptr = (int*)w;      w += align256((size_t)(NN + 1) * 4);
  int*      cursor  = (int*)w;      w += align256((size_t)NN * 4);
  float*    dinv    = (float*)w;    w += align256((size_t)NN * 4);
  int*      fid     = (int*)w;      w += align256((size_t)NN * 4);
  float*    rlpart  = (float*)w;    w += align256((size_t)64 * 4);
  int2*     epk     = (int2*)w;     w += align256((size_t)EE * 8);
  ushort_t* BT0     = (ushort_t*)w; w += align256((size_t)256 * 128 * 2);
  ushort_t* BTw     = (ushort_t*)w; w += align256((size_t)3 * 256 * 1024 * 2);
  ushort_t* agg0b   = (ushort_t*)w; w += align256((size_t)NN * 64 * 2);
  ushort_t* agg2b   = (ushort_t*)w; w += align256((size_t)NN * 512 * 2);
  ushort_t* hbuf    = (ushort_t*)w; w += align256((size_t)NN * 256 * 2);

  float* out_emb  = (float*)d_out;
  float* out_mask = out_emb + (size_t)BGR * KK * DD;
  float* out_reg  = out_emb + (size_t)out_size - 1;

  // zero deg + flag (contiguous)
  hipMemsetAsync(deg, 0, (size_t)NN * 4 + 256, stream);

  setup_kernel<<<1250 + 288, 256, 0, stream>>>(dst, s, W_in, W_out, W_in0, W_out0,
                                               b_out0, b_out, deg, fid, BTw, BT0, rlpart);
  bucket_kernel<<<(EE + 255) / 256, 256, 0, stream>>>(src, dst, mask, deg, dinv,
                                                      row_ptr, cursor, epk, bar);

  // layer 0: aggregate x, then MFMA transform + LN + ReLU
  agg0_kernel<<<NN / 4, 256, 0, stream>>>(x, epk, row_ptr, agg0b);
  gemm_mfma_ln<128><<<NN / 32, 256, 0, stream>>>(agg0b, BT0, b_in0, b_out0, ln_g, ln_b, hbuf);
  // layers 1..3
  for (int l = 0; l < LL - 1; l++) {
    agg_kernel<<<NN / 4, 256, 0, stream>>>(hbuf, epk, row_ptr, agg2b);
    gemm_mfma_ln<1024><<<NN / 32, 256, 0, stream>>>(agg2b, BTw + (size_t)l * 262144,
                                                    b_in + l * 256, b_out + l * 256,
                                                    ln_g + (l + 1) * 256, ln_b + (l + 1) * 256,
                                                    hbuf);
  }

  frag_pool_kernel<<<BGR * KK + 1, 256, 0, stream>>>(hbuf, fid, fbn_g, fbn_b, rlpart,
                                                     out_emb, out_mask, out_reg);
}

// Round 11
// 276.765 us; speedup vs baseline: 10.8118x; 1.0740x over previous
//
#include <hip/hip_runtime.h>

#define NN   10240
#define EE   320000
#define BGR  64
#define NPG  160
#define KK   16
#define DINF 25
#define DD   256
#define LL   4
#define LNEPS 1e-5f
#define BWIN 2048   // edges scanned per bucket block

typedef unsigned short ushort_t;
typedef __attribute__((ext_vector_type(8))) short s8v;
typedef __attribute__((ext_vector_type(4))) float f4v;

__device__ __forceinline__ float bf2f(ushort_t u) {
  union { unsigned u; float f; } a; a.u = ((unsigned)u) << 16; return a.f;
}
__device__ __forceinline__ ushort_t f2bf(float f) {
  union { float f; unsigned u; } a; a.f = f;
  unsigned r = (a.u + 0x7fffu + ((a.u >> 16) & 1u)) >> 16;   // RNE
  return (ushort_t)r;
}

// async global->LDS DMA, 16B per lane, dest = wave-uniform base + lane*16
__device__ __forceinline__ void gld16(const void* g, void* l) {
  __builtin_amdgcn_global_load_lds(
      (const __attribute__((address_space(1))) unsigned int*)g,
      (__attribute__((address_space(3))) unsigned int*)l, 16, 0, 0);
}

// ---------------- block reduce (256 threads = 4 waves) ----------------
__device__ __forceinline__ float2 block_reduce2(float a, float b, float* red) {
  __syncthreads();
  #pragma unroll
  for (int off = 32; off > 0; off >>= 1) {
    a += __shfl_down(a, off);
    b += __shfl_down(b, off);
  }
  int lane = threadIdx.x & 63;
  int wid  = threadIdx.x >> 6;
  if (lane == 0) { red[wid * 2] = a; red[wid * 2 + 1] = b; }
  __syncthreads();
  float sa = red[0] + red[2] + red[4] + red[6];
  float sb = red[1] + red[3] + red[5] + red[7];
  return make_float2(sa, sb);
}

// ---------------- setup (merged): degfid + weight prep + regloss partials ----------------
__global__ __launch_bounds__(256) void setup_kernel(const int* __restrict__ dst,
                                                    const float* __restrict__ s,
                                                    const float* __restrict__ Wi,
                                                    const float* __restrict__ Wo,
                                                    const float* __restrict__ Wi0,
                                                    const float* __restrict__ Wo0,
                                                    const float* __restrict__ b_out0,
                                                    const float* __restrict__ b_out,
                                                    int* __restrict__ deg,
                                                    int* __restrict__ fid,
                                                    ushort_t* __restrict__ BT,
                                                    ushort_t* __restrict__ BT0,
                                                    float* __restrict__ partials) {
  int bid0 = blockIdx.x;
  int t = threadIdx.x;
  if (bid0 < 1250) {
    int e = bid0 * 256 + t;
    if (e < EE) atomicAdd(&deg[dst[e]], 1);
    if (e < NN) {
      int k = 0;
      #pragma unroll
      for (int j = 0; j < KK; j++) if (s[e * KK + j] > 0.5f) k = j;
      fid[e] = k;
    }
    return;
  }
  int bid = bid0 - 1250;
  if (bid < 96) {
    int l = bid >> 5, rem = bid & 31;
    int kb = rem >> 2, nb = rem & 3;
    int k0 = kb * 64, n0 = nb * 64;
    __shared__ float tile[64][65];
    const float* Wl = (k0 < 256) ? (Wi + (size_t)l * 65536 + (size_t)k0 * 256)
                                 : (Wo + (size_t)l * 65536 + (size_t)(k0 - 256) * 256);
    #pragma unroll
    for (int p = 0; p < 4; p++) {
      int ks = p * 16 + (t >> 4);
      int n  = (t & 15) * 4;
      float4 v = *(const float4*)&Wl[(size_t)ks * 256 + n0 + n];
      tile[ks][n] = v.x; tile[ks][n + 1] = v.y; tile[ks][n + 2] = v.z; tile[ks][n + 3] = v.w;
    }
    __syncthreads();
    ushort_t* BTl = BT + (size_t)l * 262144;
    #pragma unroll
    for (int p = 0; p < 2; p++) {
      int n  = p * 32 + (t >> 3);
      int kk = (t & 7) * 8;
      ushort_t hi[8], lo[8];
      #pragma unroll
      for (int j = 0; j < 8; j++) {
        float v = tile[kk + j][n];
        hi[j] = f2bf(v);
        lo[j] = f2bf(v - bf2f(hi[j]));
      }
      *(s8v*)&BTl[(size_t)(n0 + n) * 1024 + k0 + kk]       = *(const s8v*)hi;
      *(s8v*)&BTl[(size_t)(n0 + n) * 1024 + 512 + k0 + kk] = *(const s8v*)lo;
    }
  } else if (bid < 224) {
    int idx = (bid - 96) * 256 + t;   // n*128 + k
    int n = idx >> 7, k = idx & 127;
    int ks = k & 63;
    float v = 0.f;
    if (ks < DINF) v = Wi0[ks * 256 + n];
    else if (ks < 2 * DINF) v = Wo0[(ks - DINF) * 256 + n];
    ushort_t hi = f2bf(v);
    BT0[idx] = (k < 64) ? hi : f2bf(v - bf2f(hi));
  } else {
    // regloss partials over |Wo0| + |b_out0| + |Wo| + |b_out|
    int rb = bid - 224;               // 0..63
    int tid = rb * 256 + t;
    int stride = 64 * 256;
    float sum = 0.f;
    for (int i = tid; i < DINF * DD; i += stride)          sum += fabsf(Wo0[i]);
    for (int i = tid; i < DD; i += stride)                 sum += fabsf(b_out0[i]);
    for (int i = tid; i < (LL - 1) * DD * DD; i += stride) sum += fabsf(Wo[i]);
    for (int i = tid; i < (LL - 1) * DD; i += stride)      sum += fabsf(b_out[i]);
    __shared__ float red[8];
    float2 ss = block_reduce2(sum, 0.f, red);
    if (t == 0) partials[rb] = ss.x;
  }
}

// ---------------- prefix scan phase 1: per-chunk sums + dinv ----------------
__global__ __launch_bounds__(256) void chunk_kernel(const int* __restrict__ deg,
                                                    float* __restrict__ dinv,
                                                    int* __restrict__ chunk_sum) {
  int t = threadIdx.x;
  int n = blockIdx.x * 256 + t;
  int d = deg[n];
  dinv[n] = rsqrtf((float)max(d, 1));
  __shared__ int red[4];
  int v = d;
  #pragma unroll
  for (int off = 32; off > 0; off >>= 1) v += __shfl_down(v, off);
  if ((t & 63) == 0) red[t >> 6] = v;
  __syncthreads();
  if (t == 0) chunk_sum[blockIdx.x] = red[0] + red[1] + red[2] + red[3];
}

// ---------------- phase 2: chunk scan (redundant per block) + node scan ----------------
__global__ __launch_bounds__(256) void rowptr_kernel(const int* __restrict__ deg,
                                                     const int* __restrict__ chunk_sum,
                                                     int* __restrict__ row_ptr,
                                                     int* __restrict__ cursor) {
  int t = threadIdx.x;
  __shared__ int coff_s;
  __shared__ int wsum[4];
  if (t < 64) {                       // wave 0 re-scans the 40 chunk sums (160 B)
    int dd2 = (t < NN / 256) ? chunk_sum[t] : 0;
    int vv = dd2;
    #pragma unroll
    for (int off = 1; off < 64; off <<= 1) {
      int u = __shfl_up(vv, off);
      if (t >= off) vv += u;
    }
    if (t == (int)blockIdx.x) coff_s = vv - dd2;     // exclusive offset of my chunk
  }
  if (blockIdx.x == 0 && t == 64) row_ptr[NN] = EE;
  int lane = t & 63;
  int wid  = t >> 6;
  int n = blockIdx.x * 256 + t;
  int d = deg[n];
  int v = d;
  #pragma unroll
  for (int off = 1; off < 64; off <<= 1) {
    int u = __shfl_up(v, off);
    if (lane >= off) v += u;
  }
  if (lane == 63) wsum[wid] = v;
  __syncthreads();
  int woff = 0;
  #pragma unroll
  for (int p = 0; p < 4; p++) woff += (p < wid) ? wsum[p] : 0;
  int rp = coff_s + woff + (v - d);
  row_ptr[n] = rp;
  cursor[n]  = rp;
}

// ---------------- XCD-range-partitioned bucketing ----------------
// Round-10 diagnosis: random 8B scatter into epk dirtied 64B lines across all 8
// XCDs' (non-coherent) L2s -> 19MB partial-line HBM writebacks, 51us. Fix: blocks
// with bid&7==r (round-robin -> XCD r) handle ONLY dst range r; epk slots for
// range r are contiguous and written by one XCD -> lines assemble in its L2 ->
// full-line writebacks (~2.6MB). dst[] read 8x (L3-cached, cheap). The mapping is
// a locality heuristic only — correctness never depends on it.
__global__ __launch_bounds__(256) void bucket_kernel(const int* __restrict__ src,
                                                     const int* __restrict__ dst,
                                                     const int* __restrict__ mask,
                                                     const float* __restrict__ dinv,
                                                     int* __restrict__ cursor,
                                                     int2* __restrict__ epk) {
  int r  = blockIdx.x & 7;            // dst range == target XCD (round-robin)
  int wb = blockIdx.x >> 3;           // edge window
  int base = wb * BWIN;
  int lo = r * (NN / 8), hi = lo + (NN / 8);
  for (int i = threadIdx.x; i < BWIN; i += 256) {
    int e = base + i;
    if (e >= EE) break;
    int dn = dst[e];
    if (dn >= lo && dn < hi) {
      int sn = src[e];
      int mk = mask[e];
      float wgt = dinv[sn] * dinv[dn];
      int p = atomicAdd(&cursor[dn], 1);
      epk[p] = make_int2(sn | (mk ? (int)0x80000000 : 0), __float_as_int(wgt));
    }
  }
}

// ---------------- layer-0 aggregation: wave-per-node, 8 edges in flight ----------------
__global__ __launch_bounds__(256) void agg0_kernel(const float* __restrict__ x,
                                                   const int2* __restrict__ epk,
                                                   const int* __restrict__ row_ptr,
                                                   ushort_t* __restrict__ agg0b) {
  int n = blockIdx.x * 4 + (threadIdx.x >> 6);
  int lane = threadIdx.x & 63;
  int half = lane >> 5;
  int ch = lane & 31;
  int chc = (ch < DINF) ? ch : 0;      // clamped safe address; unused lanes never write
  int e0 = row_ptr[n], e1 = row_ptr[n + 1];
  float accI = 0.f, accO = 0.f;
  for (int c0 = e0; c0 < e1; c0 += 64) {
    int cnt = min(64, e1 - c0);
    int2 my = (lane < cnt) ? epk[c0 + lane] : make_int2(0, 0);
    int i = half;
    for (; i + 6 < cnt; i += 8) {       // this half handles i, i+2, i+4, i+6
      unsigned u[4]; float w[4], v[4];
      #pragma unroll
      for (int j = 0; j < 4; j++) {
        u[j] = (unsigned)__shfl(my.x, i + 2 * j);
        w[j] = __int_as_float(__shfl(my.y, i + 2 * j));
      }
      #pragma unroll
      for (int j = 0; j < 4; j++)
        v[j] = x[(size_t)(u[j] & 0x7fffffffu) * DINF + chc];
      #pragma unroll
      for (int j = 0; j < 4; j++) {
        float wI = (u[j] >> 31) ? w[j] : 0.f;  float wO = w[j] - wI;
        accI = fmaf(v[j], wI, accI); accO = fmaf(v[j], wO, accO);
      }
    }
    for (; i < cnt; i += 2) {
      unsigned u = (unsigned)__shfl(my.x, i);
      float w = __int_as_float(__shfl(my.y, i));
      float v = x[(size_t)(u & 0x7fffffffu) * DINF + chc];
      float wI = (u >> 31) ? w : 0.f;  float wO = w - wI;
      accI = fmaf(v, wI, accI); accO = fmaf(v, wO, accO);
    }
  }
  accI += __shfl_xor(accI, 32);
  accO += __shfl_xor(accO, 32);
  if (half == 0) {
    if (ch < DINF) {
      agg0b[(size_t)n * 64 + ch]        = f2bf(accI);
      agg0b[(size_t)n * 64 + DINF + ch] = f2bf(accO);
    } else {
      int k = 2 * DINF + (ch - DINF) * 2;
      agg0b[(size_t)n * 64 + k] = 0;
      agg0b[(size_t)n * 64 + k + 1] = 0;
    }
  }
}

// ---------------- layer 1-3 aggregation: wave-per-node, scalar metadata, 8 in flight --
__global__ __launch_bounds__(256) void agg_kernel(const ushort_t* __restrict__ h,
                                                  const int2* __restrict__ epk,
                                                  const int* __restrict__ row_ptr,
                                                  ushort_t* __restrict__ agg2b) {
  int n = blockIdx.x * 4 + (threadIdx.x >> 6);
  int lane = threadIdx.x & 63;
  int coff = lane * 4;
  int e0 = __builtin_amdgcn_readfirstlane(row_ptr[n]);
  int e1 = __builtin_amdgcn_readfirstlane(row_ptr[n + 1]);
  float aI0 = 0.f, aI1 = 0.f, aI2 = 0.f, aI3 = 0.f;
  float aO0 = 0.f, aO1 = 0.f, aO2 = 0.f, aO3 = 0.f;
  int i = e0;
  for (; i + 8 <= e1; i += 8) {
    int2 e[8];
    #pragma unroll
    for (int j = 0; j < 8; j++) e[j] = epk[i + j];
    ushort4 v[8];
    #pragma unroll
    for (int j = 0; j < 8; j++)
      v[j] = *(const ushort4*)&h[(size_t)(unsigned)(e[j].x & 0x7fffffff) * 256u + coff];
    #pragma unroll
    for (int j = 0; j < 8; j++) {
      float w = __int_as_float(e[j].y);
      float wI = (e[j].x < 0) ? w : 0.f;  float wO = w - wI;
      float f;
      f = bf2f(v[j].x); aI0 = fmaf(f, wI, aI0); aO0 = fmaf(f, wO, aO0);
      f = bf2f(v[j].y); aI1 = fmaf(f, wI, aI1); aO1 = fmaf(f, wO, aO1);
      f = bf2f(v[j].z); aI2 = fmaf(f, wI, aI2); aO2 = fmaf(f, wO, aO2);
      f = bf2f(v[j].w); aI3 = fmaf(f, wI, aI3); aO3 = fmaf(f, wO, aO3);
    }
  }
  for (; i < e1; i++) {
    int2 e = epk[i];
    ushort4 v = *(const ushort4*)&h[(size_t)(unsigned)(e.x & 0x7fffffff) * 256u + coff];
    float w = __int_as_float(e.y);
    float wI = (e.x < 0) ? w : 0.f;  float wO = w - wI;
    float f;
    f = bf2f(v.x); aI0 = fmaf(f, wI, aI0); aO0 = fmaf(f, wO, aO0);
    f = bf2f(v.y); aI1 = fmaf(f, wI, aI1); aO1 = fmaf(f, wO, aO1);
    f = bf2f(v.z); aI2 = fmaf(f, wI, aI2); aO2 = fmaf(f, wO, aO2);
    f = bf2f(v.w); aI3 = fmaf(f, wI, aI3); aO3 = fmaf(f, wO, aO3);
  }
  ushort_t* row = &agg2b[(size_t)n * 512];
  ushort4 pI, pO;
  pI.x = f2bf(aI0); pI.y = f2bf(aI1); pI.z = f2bf(aI2); pI.w = f2bf(aI3);
  pO.x = f2bf(aO0); pO.y = f2bf(aO1); pO.z = f2bf(aO2); pO.w = f2bf(aO3);
  *(ushort4*)&row[coff]       = pI;
  *(ushort4*)&row[256 + coff] = pO;
}

// ---------------- MFMA GEMM v2 (round-2 verified): gld16 staging, swizzled LDS -------
// 4 waves x (32 rows x 64 cols); 12 ds_read_b128 : 16 MFMA per K-step; 37 KB LDS.
template <int KB>
__global__ __launch_bounds__(256, 4) void gemm_mfma_ln(const ushort_t* __restrict__ A,
                                                       const ushort_t* __restrict__ BT,
                                                       const float* __restrict__ bi,
                                                       const float* __restrict__ bo,
                                                       const float* __restrict__ g,
                                                       const float* __restrict__ bb,
                                                       ushort_t* __restrict__ hout) {
  constexpr int AK = KB / 2;               // A row length (shorts)
  constexpr int ABR = AK * 2;              // A row bytes
  constexpr int BBR = KB * 2;              // BT row bytes
  __shared__ __align__(16) ushort_t As[32 * 64];
  __shared__ __align__(16) ushort_t Bs[256 * 64];
  __shared__ float redS[32][4];
  __shared__ float redQ[32][4];
  int t = threadIdx.x;
  int m0 = blockIdx.x * 32;
  int w = t >> 6;
  int lane = t & 63;
  int q = lane >> 4, n16 = lane & 15;
  int sx = (n16 & 7) << 3;                 // read-side swizzle (short units)
  f4v acc[2][4];
  #pragma unroll
  for (int rt = 0; rt < 2; rt++)
    #pragma unroll
    for (int ct = 0; ct < 4; ct++) acc[rt][ct] = (f4v){0.f, 0.f, 0.f, 0.f};

  int srow   = lane >> 3;
  int sobyte = (lane & 7) * 16;
  int arow   = w * 8 + srow;
  size_t a_base = (size_t)(m0 + arow) * ABR
                + (size_t)((unsigned)sobyte ^ ((unsigned)(arow & 7) << 4));
  char* as_dst = (char*)As + w * 1024;
  char* bs_dst = (char*)Bs + w * 8192;

  for (int k0 = 0; k0 < KB; k0 += 64) {
    __syncthreads();                       // previous tile fully consumed
    gld16((const char*)A + a_base + (size_t)((k0 & (AK - 1)) * 2), as_dst);
    #pragma unroll
    for (int j = 0; j < 8; j++) {
      int brow = w * 64 + j * 8 + srow;
      gld16((const char*)BT + (size_t)brow * BBR + (size_t)(k0 * 2)
                + (size_t)((unsigned)sobyte ^ ((unsigned)(brow & 7) << 4)),
            bs_dst + j * 1024);
    }
    asm volatile("s_waitcnt vmcnt(0)" ::: "memory");
    __syncthreads();                       // tile ready
    #pragma unroll
    for (int kk = 0; kk < 2; kk++) {
      int ko = (kk * 32 + q * 8) ^ sx;
      s8v af0 = *(const s8v*)&As[n16 * 64 + ko];
      s8v af1 = *(const s8v*)&As[(16 + n16) * 64 + ko];
      #pragma unroll
      for (int ct = 0; ct < 4; ct++) {
        s8v bf = *(const s8v*)&Bs[(w * 64 + ct * 16 + n16) * 64 + ko];
        acc[0][ct] = __builtin_amdgcn_mfma_f32_16x16x32_bf16(af0, bf, acc[0][ct], 0, 0, 0);
        acc[1][ct] = __builtin_amdgcn_mfma_f32_16x16x32_bf16(af1, bf, acc[1][ct], 0, 0, 0);
      }
    }
  }

  // epilogue: bias, row-LN across the 4 col-quarter waves, ReLU, bf16 store
  float biv[4], gv[4], bbv[4];
  #pragma unroll
  for (int ct = 0; ct < 4; ct++) {
    int c = w * 64 + ct * 16 + n16;
    biv[ct] = bi[c] + bo[c];
    gv[ct]  = g[c];
    bbv[ct] = bb[c];
  }
  #pragma unroll
  for (int rt = 0; rt < 2; rt++)
    #pragma unroll
    for (int rg = 0; rg < 4; rg++) {
      float s = 0.f, ss = 0.f;
      #pragma unroll
      for (int ct = 0; ct < 4; ct++) {
        float v = acc[rt][ct][rg] + biv[ct];
        s += v; ss += v * v;
      }
      #pragma unroll
      for (int off = 1; off < 16; off <<= 1) {
        s  += __shfl_xor(s, off);
        ss += __shfl_xor(ss, off);
      }
      if (n16 == 0) {
        int row = rt * 16 + q * 4 + rg;
        redS[row][w] = s;
        redQ[row][w] = ss;
      }
    }
  __syncthreads();
  #pragma unroll
  for (int rt = 0; rt < 2; rt++)
    #pragma unroll
    for (int rg = 0; rg < 4; rg++) {
      int row = rt * 16 + q * 4 + rg;
      float mean = (redS[row][0] + redS[row][1] + redS[row][2] + redS[row][3]) * (1.f / 256.f);
      float var  = (redQ[row][0] + redQ[row][1] + redQ[row][2] + redQ[row][3]) * (1.f / 256.f)
                   - mean * mean;
      float rs = rsqrtf(fmaxf(var, 0.f) + LNEPS);
      #pragma unroll
      for (int ct = 0; ct < 4; ct++) {
        float v = acc[rt][ct][rg] + biv[ct];
        float o = fmaxf((v - mean) * rs * gv[ct] + bbv[ct], 0.f);
        hout[(size_t)(m0 + row) * 256 + w * 64 + ct * 16 + n16] = f2bf(o);
      }
    }
}

// ---------------- fragment pooling + LN + mask; extra block finalizes regloss --------
__global__ __launch_bounds__(256) void frag_pool_kernel(const ushort_t* __restrict__ h,
                                                        const int* __restrict__ fid,
                                                        const float* __restrict__ g,
                                                        const float* __restrict__ bb,
                                                        const float* __restrict__ partials,
                                                        float* __restrict__ out_emb,
                                                        float* __restrict__ out_mask,
                                                        float* __restrict__ out_reg) {
  int d = threadIdx.x;
  if (blockIdx.x == BGR * KK) {       // regloss final: sum 64 partials
    if (d < 64) {
      float sv = partials[d];
      #pragma unroll
      for (int off = 32; off > 0; off >>= 1) sv += __shfl_down(sv, off);
      if (d == 0) out_reg[0] = sv;
    }
    return;
  }
  int b = blockIdx.x >> 4;
  int k = blockIdx.x & 15;
  __shared__ int list[NPG];
  __shared__ int cnt;
  __shared__ float red[8];
  if (d == 0) cnt = 0;
  __syncthreads();
  int base = b * NPG;
  if (d < NPG) {
    if (fid[base + d] == k) { int p = atomicAdd(&cnt, 1); list[p] = d; }
  }
  __syncthreads();
  int c = cnt;
  float acc = 0.f;
  int i = 0;
  for (; i + 4 <= c; i += 4) {
    int l0 = list[i], l1 = list[i + 1], l2 = list[i + 2], l3 = list[i + 3];
    float a0 = bf2f(h[(size_t)(base + l0) * 256 + d]);
    float a1 = bf2f(h[(size_t)(base + l1) * 256 + d]);
    float a2 = bf2f(h[(size_t)(base + l2) * 256 + d]);
    float a3 = bf2f(h[(size_t)(base + l3) * 256 + d]);
    acc += (a0 + a1) + (a2 + a3);
  }
  for (; i < c; i++) {
    acc += bf2f(h[(size_t)(base + list[i]) * 256 + d]);
  }
  float2 ss = block_reduce2(acc, acc * acc, red);
  float mean = ss.x * (1.f / 256.f);
  float var  = ss.y * (1.f / 256.f) - mean * mean;
  float o = (acc - mean) * rsqrtf(fmaxf(var, 0.f) + LNEPS) * g[d] + bb[d];
  out_emb[((size_t)b * KK + k) * 256 + d] = o;
  if (d == 0) out_mask[b * KK + k] = (c > 0) ? 1.f : 0.f;
}

// ---------------- launch ----------------
static inline size_t align256(size_t x) { return (x + 255) & ~(size_t)255; }

extern "C" void kernel_launch(void* const* d_in, const int* in_sizes, int n_in,
                              void* d_out, int out_size, void* d_ws, size_t ws_size,
                              hipStream_t stream) {
  const float* x      = (const float*)d_in[0];
  const int*   ei     = (const int*)d_in[1];
  const int*   mask   = (const int*)d_in[2];
  const float* s      = (const float*)d_in[3];
  const float* W_in0  = (const float*)d_in[5];
  const float* W_out0 = (const float*)d_in[6];
  const float* b_in0  = (const float*)d_in[7];
  const float* b_out0 = (const float*)d_in[8];
  const float* W_in   = (const float*)d_in[9];
  const float* W_out  = (const float*)d_in[10];
  const float* b_in   = (const float*)d_in[11];
  const float* b_out  = (const float*)d_in[12];
  const float* ln_g   = (const float*)d_in[13];
  const float* ln_b   = (const float*)d_in[14];
  const float* fbn_g  = (const float*)d_in[15];
  const float* fbn_b  = (const float*)d_in[16];

  const int* src = ei;
  const int* dst = ei + EE;

  char* w = (char*)d_ws;
  int*      deg     = (int*)w;      w += align256((size_t)NN * 4);
  int*      row_ptr = (int*)w;      w += align256((size_t)(NN + 1) * 4);
  int*      cursor  = (int*)w;      w += align256((size_t)NN * 4);
  float*    dinv    = (float*)w;    w += align256((size_t)NN * 4);
  int*      fid     = (int*)w;      w += align256((size_t)NN * 4);
  int*      chunks  = (int*)w;      w += align256((size_t)(NN / 256) * 4);
  float*    rlpart  = (float*)w;    w += align256((size_t)64 * 4);
  int2*     epk     = (int2*)w;     w += align256((size_t)EE * 8);
  ushort_t* BT0     = (ushort_t*)w; w += align256((size_t)256 * 128 * 2);
  ushort_t* BTw     = (ushort_t*)w; w += align256((size_t)3 * 256 * 1024 * 2);
  ushort_t* agg0b   = (ushort_t*)w; w += align256((size_t)NN * 64 * 2);
  ushort_t* agg2b   = (ushort_t*)w; w += align256((size_t)NN * 512 * 2);
  ushort_t* hbuf    = (ushort_t*)w; w += align256((size_t)NN * 256 * 2);

  float* out_emb  = (float*)d_out;
  float* out_mask = out_emb + (size_t)BGR * KK * DD;
  float* out_reg  = out_emb + (size_t)out_size - 1;

  hipMemsetAsync(deg, 0, (size_t)NN * 4, stream);
  setup_kernel<<<1250 + 288, 256, 0, stream>>>(dst, s, W_in, W_out, W_in0, W_out0,
                                               b_out0, b_out, deg, fid, BTw, BT0, rlpart);
  chunk_kernel<<<NN / 256, 256, 0, stream>>>(deg, dinv, chunks);
  rowptr_kernel<<<NN / 256, 256, 0, stream>>>(deg, chunks, row_ptr, cursor);
  bucket_kernel<<<8 * ((EE + BWIN - 1) / BWIN), 256, 0, stream>>>(src, dst, mask, dinv,
                                                                  cursor, epk);

  // layer 0: aggregate x, then MFMA transform + LN + ReLU
  agg0_kernel<<<NN / 4, 256, 0, stream>>>(x, epk, row_ptr, agg0b);
  gemm_mfma_ln<128><<<NN / 32, 256, 0, stream>>>(agg0b, BT0, b_in0, b_out0, ln_g, ln_b, hbuf);
  // layers 1..3
  for (int l = 0; l < LL - 1; l++) {
    agg_kernel<<<NN / 4, 256, 0, stream>>>(hbuf, epk, row_ptr, agg2b);
    gemm_mfma_ln<1024><<<NN / 32, 256, 0, stream>>>(agg2b, BTw + (size_t)l * 262144,
                                                    b_in + l * 256, b_out + l * 256,
                                                    ln_g + (l + 1) * 256, ln_b + (l + 1) * 256,
                                                    hbuf);
  }

  frag_pool_kernel<<<BGR * KK + 1, 256, 0, stream>>>(hbuf, fid, fbn_g, fbn_b, rlpart,
                                                     out_emb, out_mask, out_reg);
}